// Round 1
// baseline (3043.370 us; speedup 1.0000x reference)
//
#include <hip/hip_runtime.h>
#include <math.h>

// ---------------------------------------------------------------------------
// Brain_49374944035335: CNN backbone (7 conv layers, BN on 1-2, maxpools) +
// 16-node MLP "colons" run twice (zero-neighbor pass, neighbor-gather pass).
// Round 0: correctness-first fp32 implementation. Convs = implicit GEMM with
// 64x64 block tile / 4x4 register tile, LDS staging. conv7 uses split-K=4.
// ---------------------------------------------------------------------------

#define BN_EPS 1e-5f

// ---------------- conv 3x3 SAME, NCHW, implicit GEMM -----------------------
// A = weights [COUT][CIN*9], B = im2col [CIN*9][B*H*W], C = out NCHW.
// grid.x = pixel tiles (N/64), grid.y = cout tiles (COUT/64), grid.z = KSPLIT.
template <int CIN, int COUT, int H, int W, int KSPLIT, bool BIAS_RELU>
__global__ __launch_bounds__(256)
void conv3x3_kernel(const float* __restrict__ in, const float* __restrict__ wgt,
                    const float* __restrict__ bias, float* __restrict__ out, int B)
{
    constexpr int K  = CIN * 9;
    constexpr int HW = H * W;
    constexpr int BK = 16;

    __shared__ __align__(16) float As[BK][68];
    __shared__ __align__(16) float Bs[BK][68];

    const int tid  = threadIdx.x;
    const int tx   = tid & 15;   // pixel quad
    const int ty   = tid >> 4;   // cout quad
    const int pix0 = blockIdx.x * 64;
    const int co0  = blockIdx.y * 64;

    // loader mappings
    const int a_co = tid >> 2;        // 0..63
    const int a_k4 = (tid & 3) * 4;   // 0,4,8,12
    const int b_p  = tid & 63;        // 0..63
    const int b_kr = tid >> 6;        // 0..3

    // pixel coords for the B (im2col) loads
    const int gp = pix0 + b_p;
    const int pb = gp / HW;
    const int pr = gp - pb * HW;
    const int py = pr / W;
    const int px = pr - py * W;
    const float* inb = in + (size_t)pb * (CIN * HW);

    float acc[4][4];
#pragma unroll
    for (int i = 0; i < 4; ++i)
#pragma unroll
        for (int j = 0; j < 4; ++j) acc[i][j] = 0.f;

    constexpr int kIters = (K + BK - 1) / BK;
    int it0 = 0, it1 = kIters;
    if (KSPLIT > 1) {
        const int itPerZ = kIters / KSPLIT;
        it0 = blockIdx.z * itPerZ;
        it1 = (blockIdx.z == KSPLIT - 1) ? kIters : it0 + itPerZ;
    }

    for (int it = it0; it < it1; ++it) {
        const int kb = it * BK;
        // ---- A tile: 64 couts x 16 k
        if (K % 4 == 0) {
            const float4 av = *reinterpret_cast<const float4*>(
                &wgt[(size_t)(co0 + a_co) * K + kb + a_k4]);
            As[a_k4 + 0][a_co] = av.x;
            As[a_k4 + 1][a_co] = av.y;
            As[a_k4 + 2][a_co] = av.z;
            As[a_k4 + 3][a_co] = av.w;
        } else {
#pragma unroll
            for (int i = 0; i < 4; ++i) {
                const int k = kb + a_k4 + i;
                As[a_k4 + i][a_co] = (k < K) ? wgt[(size_t)(co0 + a_co) * K + k] : 0.f;
            }
        }
        // ---- B tile: 16 k x 64 pixels (on-the-fly im2col)
#pragma unroll
        for (int i = 0; i < 4; ++i) {
            const int kl = b_kr + i * 4;
            const int gk = kb + kl;
            float v = 0.f;
            if ((K % BK == 0) || (gk < K)) {
                const int ci = gk / 9;
                const int r9 = gk - ci * 9;
                const int ky = r9 / 3;
                const int kx = r9 - ky * 3;
                const int iy = py + ky - 1;
                const int ix = px + kx - 1;
                if ((unsigned)iy < (unsigned)H && (unsigned)ix < (unsigned)W)
                    v = inb[(size_t)ci * HW + iy * W + ix];
            }
            Bs[kl][b_p] = v;
        }
        __syncthreads();
#pragma unroll
        for (int kk = 0; kk < BK; ++kk) {
            const float4 av = *reinterpret_cast<const float4*>(&As[kk][ty * 4]);
            const float4 bv = *reinterpret_cast<const float4*>(&Bs[kk][tx * 4]);
            const float a0[4] = {av.x, av.y, av.z, av.w};
            const float b0[4] = {bv.x, bv.y, bv.z, bv.w};
#pragma unroll
            for (int i = 0; i < 4; ++i)
#pragma unroll
                for (int j = 0; j < 4; ++j)
                    acc[i][j] += a0[i] * b0[j];
        }
        __syncthreads();
    }

    // epilogue: this thread owns pixels p0..p0+3 (same image row) x 4 couts
    const int p0  = pix0 + tx * 4;
    const int ob  = p0 / HW;
    const int orr = p0 - ob * HW;
    const int oy  = orr / W;
    const int ox  = orr - oy * W;
    float* outz = out;
    if (KSPLIT > 1) outz += (size_t)blockIdx.z * B * COUT * HW;

#pragma unroll
    for (int i = 0; i < 4; ++i) {
        const int co = co0 + ty * 4 + i;
        float4 v = make_float4(acc[i][0], acc[i][1], acc[i][2], acc[i][3]);
        if (BIAS_RELU) {
            const float bv = bias[co];
            v.x = fmaxf(v.x + bv, 0.f);
            v.y = fmaxf(v.y + bv, 0.f);
            v.z = fmaxf(v.z + bv, 0.f);
            v.w = fmaxf(v.w + bv, 0.f);
        }
        *reinterpret_cast<float4*>(&outz[((size_t)(ob * COUT + co)) * HW + oy * W + ox]) = v;
    }
}

// ---------------- BN batch statistics --------------------------------------
template <int C, int HW>
__global__ __launch_bounds__(256)
void bn_stats_kernel(const float* __restrict__ in, float* __restrict__ sums, int B)
{
    const int c  = blockIdx.x;
    const int nb = blockIdx.y;   // 64 chunks per channel
    const int total = B * HW;
    const int chunk = total / 64;
    float s = 0.f, s2 = 0.f;
    for (int e = nb * chunk + threadIdx.x; e < (nb + 1) * chunk; e += 256) {
        const int b  = e / HW;       // HW is a power of two
        const int sp = e & (HW - 1);
        const float v = in[((size_t)(b * C + c)) * HW + sp];
        s += v; s2 += v * v;
    }
#pragma unroll
    for (int off = 32; off > 0; off >>= 1) {
        s  += __shfl_down(s, off);
        s2 += __shfl_down(s2, off);
    }
    __shared__ float red[8];
    const int wid = threadIdx.x >> 6;
    if ((threadIdx.x & 63) == 0) { red[wid] = s; red[4 + wid] = s2; }
    __syncthreads();
    if (threadIdx.x == 0) {
        const float S  = red[0] + red[1] + red[2] + red[3];
        const float S2 = red[4] + red[5] + red[6] + red[7];
        atomicAdd(&sums[c], S);
        atomicAdd(&sums[C + c], S2);
    }
}

template <int C>
__global__ void bn_finalize_kernel(const float* __restrict__ sums,
                                   const float* __restrict__ g,
                                   const float* __restrict__ beta,
                                   float* __restrict__ ss, int Ntot)
{
    const int c = blockIdx.x * 64 + threadIdx.x;
    if (c >= C) return;
    const float inv   = 1.f / (float)Ntot;
    const float mean  = sums[c] * inv;
    const float var   = sums[C + c] * inv - mean * mean;
    const float scale = g[c] * rsqrtf(var + BN_EPS);
    ss[c]     = scale;
    ss[C + c] = beta[c] - mean * scale;
}

// ---------------- maxpool k3 s2 p1 (optionally fused BN+ReLU) --------------
template <int C, int Hin, int Win, bool DO_BN>
__global__ __launch_bounds__(256)
void maxpool_kernel(const float* __restrict__ in, const float* __restrict__ ss,
                    float* __restrict__ out, int B)
{
    constexpr int Ho = Hin / 2, Wo = Win / 2;
    const int t = blockIdx.x * 256 + threadIdx.x;
    const int total = B * C * Ho * Wo;
    if (t >= total) return;
    const int ox = t % Wo;
    const int oy = (t / Wo) % Ho;
    const int c  = (t / (Wo * Ho)) % C;
    const int b  = t / (Wo * Ho * C);
    float scale = 1.f, shift = 0.f;
    if (DO_BN) { scale = ss[c]; shift = ss[C + c]; }
    const float* ip = in + ((size_t)(b * C + c)) * (Hin * Win);
    const int y0 = max(0, 2 * oy - 1), y1 = min(Hin - 1, 2 * oy + 1);
    const int x0 = max(0, 2 * ox - 1), x1 = min(Win - 1, 2 * ox + 1);
    float m = -1e30f;
    for (int iy = y0; iy <= y1; ++iy)
        for (int ix = x0; ix <= x1; ++ix) {
            float v = ip[iy * Win + ix];
            if (DO_BN) v = v * scale + shift;
            m = fmaxf(m, v);
        }
    if (DO_BN) m = fmaxf(m, 0.f);  // relu commutes with max
    out[t] = m;
}

// ---------------- conv7 partial-sum + bias + relu -> feats part of X -------
// part: 4 split-K partials, each [B][512][16]. X: [16][B][592], cols 80..591.
__global__ __launch_bounds__(256)
void build_x_feats_kernel(const float* __restrict__ part, const float* __restrict__ bias,
                          float* __restrict__ X, int B)
{
    const int t = blockIdx.x * 256 + threadIdx.x;
    if (t >= B * 512) return;
    const int b = t >> 9;
    const int c = t & 511;
    const size_t S = (size_t)B * 512 * 16;
    const float* p0 = part + ((size_t)(b * 512 + c)) * 16;
    float v[16];
#pragma unroll
    for (int q = 0; q < 16; ++q) v[q] = 0.f;
#pragma unroll
    for (int z = 0; z < 4; ++z) {
        const float* pz = p0 + z * S;
#pragma unroll
        for (int q = 0; q < 4; ++q) {
            const float4 f = *reinterpret_cast<const float4*>(&pz[q * 4]);
            v[q * 4 + 0] += f.x;
            v[q * 4 + 1] += f.y;
            v[q * 4 + 2] += f.z;
            v[q * 4 + 3] += f.w;
        }
    }
    const float bb = bias[c];
#pragma unroll
    for (int n = 0; n < 16; ++n) {
        const float r = fmaxf(v[n] + bb, 0.f);
        X[((size_t)(n * B + b)) * 592 + 80 + c] = r;
    }
}

// ---------------- colons fc1: h = tanh(X @ W1 + b1), batched over 16 nodes -
// grid: (ceil(600/64)=10, B/64, 16). 64x64 tile, 4x4 per thread.
__global__ __launch_bounds__(256)
void colon_fc1_kernel(const float* __restrict__ X, const float* __restrict__ W1,
                      const float* __restrict__ b1, float* __restrict__ h, int B)
{
    constexpr int N = 600, K = 592, BK = 16;
    const int n  = blockIdx.z;
    const int m0 = blockIdx.y * 64;
    const int o0 = blockIdx.x * 64;

    __shared__ __align__(16) float As[BK][68];
    __shared__ __align__(16) float Bs[BK][68];

    const int tid = threadIdx.x;
    const int tx = tid & 15, ty = tid >> 4;
    const int a_m = tid >> 2, a_k4 = (tid & 3) * 4;
    const int b_o = tid & 63, b_kr = tid >> 6;

    const float* Xn  = X  + (size_t)n * B * K;
    const float* W1n = W1 + (size_t)n * K * N;

    float acc[4][4];
#pragma unroll
    for (int i = 0; i < 4; ++i)
#pragma unroll
        for (int j = 0; j < 4; ++j) acc[i][j] = 0.f;

    for (int kb = 0; kb < K; kb += BK) {
        const float4 av = *reinterpret_cast<const float4*>(
            &Xn[(size_t)(m0 + a_m) * K + kb + a_k4]);
        As[a_k4 + 0][a_m] = av.x;
        As[a_k4 + 1][a_m] = av.y;
        As[a_k4 + 2][a_m] = av.z;
        As[a_k4 + 3][a_m] = av.w;
#pragma unroll
        for (int i = 0; i < 4; ++i) {
            const int kl = b_kr + i * 4;
            const int o  = o0 + b_o;
            Bs[kl][b_o] = (o < N) ? W1n[(size_t)(kb + kl) * N + o] : 0.f;
        }
        __syncthreads();
#pragma unroll
        for (int kk = 0; kk < BK; ++kk) {
            const float4 a4 = *reinterpret_cast<const float4*>(&As[kk][ty * 4]);
            const float4 b4 = *reinterpret_cast<const float4*>(&Bs[kk][tx * 4]);
            const float a0[4] = {a4.x, a4.y, a4.z, a4.w};
            const float b0[4] = {b4.x, b4.y, b4.z, b4.w};
#pragma unroll
            for (int i = 0; i < 4; ++i)
#pragma unroll
                for (int j = 0; j < 4; ++j)
                    acc[i][j] += a0[i] * b0[j];
        }
        __syncthreads();
    }

#pragma unroll
    for (int i = 0; i < 4; ++i) {
        const int m = m0 + ty * 4 + i;
#pragma unroll
        for (int j = 0; j < 4; ++j) {
            const int o = o0 + tx * 4 + j;
            if (o < N)
                h[((size_t)(n * B + m)) * N + o] = tanhf(acc[i][j] + b1[n * N + o]);
        }
    }
}

// ---------------- colons fc2 + softmax -------------------------------------
__global__ __launch_bounds__(128)
void colon_fc2_kernel(const float* __restrict__ h, const float* __restrict__ W2,
                      const float* __restrict__ b2, float* __restrict__ preds, int B)
{
    const int n = blockIdx.x;
    __shared__ float W2s[6000];
    __shared__ float b2s[10];
    for (int i = threadIdx.x; i < 6000; i += 128) W2s[i] = W2[n * 6000 + i];
    if (threadIdx.x < 10) b2s[threadIdx.x] = b2[n * 10 + threadIdx.x];
    __syncthreads();

    for (int b = threadIdx.x; b < B; b += 128) {
        float l[10];
#pragma unroll
        for (int c = 0; c < 10; ++c) l[c] = b2s[c];
        const float* hp = h + ((size_t)(n * B + b)) * 600;
        for (int k = 0; k < 600; k += 4) {
            const float4 hv = *reinterpret_cast<const float4*>(&hp[k]);
            const float hh[4] = {hv.x, hv.y, hv.z, hv.w};
#pragma unroll
            for (int u = 0; u < 4; ++u)
#pragma unroll
                for (int c = 0; c < 10; ++c)
                    l[c] += hh[u] * W2s[(k + u) * 10 + c];
        }
        float mx = l[0];
#pragma unroll
        for (int c = 1; c < 10; ++c) mx = fmaxf(mx, l[c]);
        float s = 0.f;
#pragma unroll
        for (int c = 0; c < 10; ++c) { l[c] = expf(l[c] - mx); s += l[c]; }
        const float inv = 1.f / s;
        float* pp = preds + ((size_t)(n * B + b)) * 10;
#pragma unroll
        for (int c = 0; c < 10; ++c) pp[c] = l[c] * inv;
    }
}

// ---------------- neighbor gather into X cols 0..79 ------------------------
__global__ __launch_bounds__(256)
void fill_neigh_kernel(const float* __restrict__ preds1, float* __restrict__ X, int B)
{
    const int t = blockIdx.x * 256 + threadIdx.x;
    if (t >= 16 * B * 80) return;
    const int c = t % 10;
    const int j = (t / 10) & 7;
    const int b = (t / 80) % B;
    const int n = t / (80 * B);

    // exact port of Brain.neighbors for a 4x4 grid, mode=8
    int lst[8];
    int cnt = 0;
    const int w = 4, sz = 16, i = n;
    if (i - w >= 0)                                lst[cnt++] = i - w;
    if (i % w != 0)                                lst[cnt++] = i - 1;
    if ((i + 1) % w != 0)                          lst[cnt++] = i + 1;
    if (i + w < sz)                                lst[cnt++] = i + w;
    if (i - w - 1 >= 0 && i % w != 0)              lst[cnt++] = i - w - 1;
    if (i - w + 1 >= 0 && (i + 1) % w != 0)        lst[cnt++] = i - w + 1;
    if (i + w - 1 < sz && i % w != 0)              lst[cnt++] = i + w - 1;
    if (i + w + 1 < sz && (i + 1) % w != 0)        lst[cnt++] = i + w + 1;

    float v = 0.f;
    if (j < cnt) v = preds1[((size_t)(lst[j] * B + b)) * 10 + c];
    X[((size_t)(n * B + b)) * 592 + j * 10 + c] = v;
}

// ---------------- final: out0 = (mean over nodes preds2)^2 -----------------
__global__ __launch_bounds__(256)
void final_out_kernel(const float* __restrict__ preds2, float* __restrict__ out0, int B)
{
    const int t = blockIdx.x * 256 + threadIdx.x;
    if (t >= B * 10) return;
    const int b = t / 10, c = t % 10;
    float s = 0.f;
#pragma unroll
    for (int n = 0; n < 16; ++n)
        s += preds2[((size_t)(n * B + b)) * 10 + c];
    const float m = s * (1.f / 16.f);
    out0[t] = m * m;
}

// ---------------------------------------------------------------------------
extern "C" void kernel_launch(void* const* d_in, const int* in_sizes, int n_in,
                              void* d_out, int out_size, void* d_ws, size_t ws_size,
                              hipStream_t stream)
{
    const float* x    = (const float*)d_in[0];
    const float* cw1  = (const float*)d_in[1];
    // cb1 (d_in[2]) is absorbed by train-mode BN (shift cancels in x-mean)
    const float* bn1g = (const float*)d_in[3];
    const float* bn1b = (const float*)d_in[4];
    const float* cw2  = (const float*)d_in[5];
    // cb2 (d_in[6]) likewise absorbed by BN
    const float* bn2g = (const float*)d_in[7];
    const float* bn2b = (const float*)d_in[8];
    const float* cw3  = (const float*)d_in[9];
    const float* cb3  = (const float*)d_in[10];
    const float* cw4  = (const float*)d_in[11];
    const float* cb4  = (const float*)d_in[12];
    const float* cw5  = (const float*)d_in[13];
    const float* cb5  = (const float*)d_in[14];
    const float* cw6  = (const float*)d_in[15];
    const float* cb6  = (const float*)d_in[16];
    const float* cw7  = (const float*)d_in[17];
    const float* cb7  = (const float*)d_in[18];
    const float* W1   = (const float*)d_in[19];
    const float* b1   = (const float*)d_in[20];
    const float* W2   = (const float*)d_in[21];
    const float* b2   = (const float*)d_in[22];

    const int B = in_sizes[0] / (3 * 64 * 64);   // 128

    // ---- workspace layout (floats) ----
    float* ws    = (float*)d_ws;
    float* buf0  = ws;                       // 33,554,432 floats (134 MB)
    float* buf1  = ws + 33554432;            // 16,777,216 floats (67 MB)
    float* small = ws + 50331648;
    float* sums1  = small;                   // 128 used
    float* sums2  = small + 256;             // 256 used
    float* ss1    = small + 1024;            // 128 used
    float* ss2    = small + 1536;            // 256 used
    float* preds1 = small + 2048;            // 16*B*10
    float* Xb     = buf1 + 2097152;          // 16*B*592 (past pool4 output)
    float* hb     = buf0 + 8388608;          // 16*B*600 (past conv7 partials)

    float* out0   = (float*)d_out;           // [B,10]
    float* preds2 = (float*)d_out + (size_t)B * 10;  // [16,B,10]

    // zero BN stat accumulators (ws is poisoned before every launch)
    hipMemsetAsync(small, 0, 512 * sizeof(float), stream);

    // ---- backbone ----
    // conv1: 3->64 @64x64
    conv3x3_kernel<3, 64, 64, 64, 1, false>
        <<<dim3(B * 4096 / 64, 1, 1), 256, 0, stream>>>(x, cw1, nullptr, buf0, B);
    bn_stats_kernel<64, 4096><<<dim3(64, 64), 256, 0, stream>>>(buf0, sums1, B);
    bn_finalize_kernel<64><<<1, 64, 0, stream>>>(sums1, bn1g, bn1b, ss1, B * 4096);
    maxpool_kernel<64, 64, 64, true>
        <<<(B * 64 * 32 * 32 + 255) / 256, 256, 0, stream>>>(buf0, ss1, buf1, B);

    // conv2: 64->128 @32x32
    conv3x3_kernel<64, 128, 32, 32, 1, false>
        <<<dim3(B * 1024 / 64, 2, 1), 256, 0, stream>>>(buf1, cw2, nullptr, buf0, B);
    bn_stats_kernel<128, 1024><<<dim3(128, 64), 256, 0, stream>>>(buf0, sums2, B);
    bn_finalize_kernel<128><<<2, 64, 0, stream>>>(sums2, bn2g, bn2b, ss2, B * 1024);
    maxpool_kernel<128, 32, 32, true>
        <<<(B * 128 * 16 * 16 + 255) / 256, 256, 0, stream>>>(buf0, ss2, buf1, B);

    // conv3: 128->256 @16x16 (+bias+relu)
    conv3x3_kernel<128, 256, 16, 16, 1, true>
        <<<dim3(B * 256 / 64, 4, 1), 256, 0, stream>>>(buf1, cw3, cb3, buf0, B);
    // conv4: 256->256 @16x16 (+bias+relu), then pool
    conv3x3_kernel<256, 256, 16, 16, 1, true>
        <<<dim3(B * 256 / 64, 4, 1), 256, 0, stream>>>(buf0, cw4, cb4, buf1, B);
    maxpool_kernel<256, 16, 16, false>
        <<<(B * 256 * 8 * 8 + 255) / 256, 256, 0, stream>>>(buf1, nullptr, buf0, B);

    // conv5: 256->512 @8x8
    conv3x3_kernel<256, 512, 8, 8, 1, true>
        <<<dim3(B * 64 / 64, 8, 1), 256, 0, stream>>>(buf0, cw5, cb5, buf1, B);
    // conv6: 512->512 @8x8, then pool
    conv3x3_kernel<512, 512, 8, 8, 1, true>
        <<<dim3(B * 64 / 64, 8, 1), 256, 0, stream>>>(buf1, cw6, cb6, buf0, B);
    maxpool_kernel<512, 8, 8, false>
        <<<(B * 512 * 4 * 4 + 255) / 256, 256, 0, stream>>>(buf0, nullptr, buf1, B);

    // conv7: 512->512 @4x4, split-K=4 into partials (bias/relu in build_x)
    conv3x3_kernel<512, 512, 4, 4, 4, false>
        <<<dim3(B * 16 / 64, 8, 4), 256, 0, stream>>>(buf1, cw7, nullptr, buf0, B);

    // ---- colons ----
    // X = [16][B][592]; zero (pass-1 neighbor slots), fill feats cols 80..591
    hipMemsetAsync(Xb, 0, (size_t)16 * B * 592 * sizeof(float), stream);
    build_x_feats_kernel<<<(B * 512 + 255) / 256, 256, 0, stream>>>(buf0, cb7, Xb, B);

    // pass 1
    colon_fc1_kernel<<<dim3(10, B / 64, 16), 256, 0, stream>>>(Xb, W1, b1, hb, B);
    colon_fc2_kernel<<<16, 128, 0, stream>>>(hb, W2, b2, preds1, B);

    // pass 2: gather neighbor predictions into X cols 0..79
    fill_neigh_kernel<<<(16 * B * 80 + 255) / 256, 256, 0, stream>>>(preds1, Xb, B);
    colon_fc1_kernel<<<dim3(10, B / 64, 16), 256, 0, stream>>>(Xb, W1, b1, hb, B);
    colon_fc2_kernel<<<16, 128, 0, stream>>>(hb, W2, b2, preds2, B);

    // final squared-mean
    final_out_kernel<<<(B * 10 + 255) / 256, 256, 0, stream>>>(preds2, out0, B);
}

// Round 2
// 1082.083 us; speedup vs baseline: 2.8125x; 2.8125x over previous
//
#include <hip/hip_runtime.h>
#include <math.h>

// ---------------------------------------------------------------------------
// Brain_49374944035335  R2: convs 2-7 -> f16 MFMA (16x16x32), 9-shifted-GEMM
// decomposition (no im2col division), 128x128 tile, fp32 accumulate.
// conv1 / colons / pools stay fp32.
// ---------------------------------------------------------------------------

#define BN_EPS 1e-5f

typedef _Float16 f16x8 __attribute__((ext_vector_type(8)));
typedef float    f32x4v __attribute__((ext_vector_type(4)));

constexpr int ilog2c(int x) { return x <= 1 ? 0 : 1 + ilog2c(x >> 1); }

// ---------------- weight pre-transform: OIHW fp32 -> [9][CO*CI] f16 --------
__global__ __launch_bounds__(256)
void wsplit_kernel(const float* __restrict__ w, _Float16* __restrict__ o, int COCI)
{
    const int t = blockIdx.x * 256 + threadIdx.x;
    if (t >= COCI) return;
#pragma unroll
    for (int ph = 0; ph < 9; ++ph)
        o[ph * COCI + t] = (_Float16)w[t * 9 + ph];
}

// ---------------- MFMA conv: 3x3 SAME as 9 shifted GEMMs -------------------
// A = w9[ph][CO][CI] (f16), B = shifted input (fp32->f16 on stage).
// Block: 256 thr = 4 waves; C tile 128(cout) x 128(pixels); BK = 32 (ci).
template <int CI, int CO, int H, int W, int KSPLIT, bool BIAS_RELU>
__global__ __launch_bounds__(256)
void conv_mfma_kernel(const float* __restrict__ in, const _Float16* __restrict__ w9,
                      const float* __restrict__ bias, float* __restrict__ out, int B)
{
    constexpr int HW   = H * W;
    constexpr int lgHW = ilog2c(HW);
    constexpr int lgW  = ilog2c(W);

    __shared__ _Float16 As[128 * 32];
    __shared__ _Float16 Bs[128 * 32];

    const int tid  = threadIdx.x;
    const int pix0 = blockIdx.x * 128;
    const int co0  = blockIdx.y * 128;

    // ---- B staging ids: thread -> (pixel bn, ci-half bh) ----
    const int bn = tid & 127;
    const int bh = tid >> 7;              // 0/1 -> ci 16*bh .. +15
    const int gp = pix0 + bn;
    const int pb = gp >> lgHW;
    const int sp = gp & (HW - 1);
    const int py = sp >> lgW;
    const int px = sp & (W - 1);
    const float* inb = in + ((size_t)(pb * CI) << lgHW);

    // ---- A staging ids: thread -> (row, 16-f16 half) ----
    const int arow = tid >> 1;
    const int acl  = (tid & 1) * 16;

    // ---- wave/frag ids ----
    const int lane = tid & 63;
    const int wv   = tid >> 6;
    const int wm   = (wv & 1) * 64;
    const int wn   = (wv >> 1) * 64;
    const int q    = lane >> 4;
    const int lm   = lane & 15;
    const int bsw  = (q ^ (lm & 3)) << 3;   // swizzled B chunk offset (f16)

    f32x4v acc[4][4];
#pragma unroll
    for (int i = 0; i < 4; ++i)
#pragma unroll
        for (int j = 0; j < 4; ++j) acc[i][j] = (f32x4v)0.f;

    constexpr int CS_TOT = CI / 32;
    constexpr int CS_PER = CS_TOT / KSPLIT;
    const int cs0 = (KSPLIT > 1) ? blockIdx.z * CS_PER : 0;

    for (int ph = 0; ph < 9; ++ph) {
        const int dy = ph / 3 - 1;
        const int dx = ph - (ph / 3) * 3 - 1;
        const int y2 = py + dy;
        const int x2 = px + dx;
        const bool valid = ((unsigned)y2 < (unsigned)H) && ((unsigned)x2 < (unsigned)W);
        const float msk = valid ? 1.f : 0.f;
        const int off = valid ? ((y2 << lgW) + x2) : 0;
        const float* bsrc = inb + ((size_t)(bh * 16) << lgHW) + off;
        const _Float16* asrc = w9 + ((size_t)(ph * CO + co0 + arow)) * CI + acl;

        for (int cs = cs0; cs < cs0 + CS_PER; ++cs) {
            // global loads (overlap previous tile's MFMA)
            const f16x8 a0 = *(const f16x8*)(asrc + cs * 32);
            const f16x8 a1 = *(const f16x8*)(asrc + cs * 32 + 8);
            float bv[16];
            const float* bp = bsrc + ((size_t)(cs * 32) << lgHW);
#pragma unroll
            for (int u = 0; u < 16; ++u) bv[u] = bp[(size_t)u << lgHW];

            __syncthreads();   // previous tile fully consumed
            *(f16x8*)&As[arow * 32 + acl]     = a0;
            *(f16x8*)&As[arow * 32 + acl + 8] = a1;
            f16x8 p0, p1;
#pragma unroll
            for (int u = 0; u < 8; ++u) p0[u] = (_Float16)(bv[u] * msk);
#pragma unroll
            for (int u = 0; u < 8; ++u) p1[u] = (_Float16)(bv[8 + u] * msk);
            const int o0 = ((2 * bh) ^ (bn & 3)) << 3;
            const int o1 = ((2 * bh + 1) ^ (bn & 3)) << 3;
            *(f16x8*)&Bs[bn * 32 + o0] = p0;
            *(f16x8*)&Bs[bn * 32 + o1] = p1;
            __syncthreads();

            f16x8 af[4], bf[4];
#pragma unroll
            for (int ti = 0; ti < 4; ++ti)
                af[ti] = *(const f16x8*)&As[(wm + ti * 16 + lm) * 32 + (q << 3)];
#pragma unroll
            for (int tj = 0; tj < 4; ++tj)
                bf[tj] = *(const f16x8*)&Bs[(wn + tj * 16 + lm) * 32 + bsw];
#pragma unroll
            for (int ti = 0; ti < 4; ++ti)
#pragma unroll
                for (int tj = 0; tj < 4; ++tj)
                    acc[ti][tj] = __builtin_amdgcn_mfma_f32_16x16x32_f16(
                        af[ti], bf[tj], acc[ti][tj], 0, 0, 0);
        }
    }

    // ---- epilogue: C[row=cout][col=pixel], col=lane&15, row=quad*4+reg ----
    float* outz = out;
    if (KSPLIT > 1) outz += (size_t)blockIdx.z * B * CO * HW;

#pragma unroll
    for (int tj = 0; tj < 4; ++tj) {
        const int gpix = pix0 + wn + tj * 16 + lm;
        const int opb  = gpix >> lgHW;
        const int osp  = gpix & (HW - 1);
#pragma unroll
        for (int ti = 0; ti < 4; ++ti) {
            const int cob = co0 + wm + ti * 16 + q * 4;
#pragma unroll
            for (int r = 0; r < 4; ++r) {
                float v = acc[ti][tj][r];
                if (BIAS_RELU) v = fmaxf(v + bias[cob + r], 0.f);
                outz[((size_t)(opb * CO + cob + r) << lgHW) + osp] = v;
            }
        }
    }
}

// ---------------- fp32 conv (conv1 only, K=27) -----------------------------
template <int CIN, int COUT, int H, int W, int KSPLIT, bool BIAS_RELU>
__global__ __launch_bounds__(256)
void conv3x3_kernel(const float* __restrict__ in, const float* __restrict__ wgt,
                    const float* __restrict__ bias, float* __restrict__ out, int B)
{
    constexpr int K  = CIN * 9;
    constexpr int HW = H * W;
    constexpr int BK = 16;

    __shared__ __align__(16) float As[BK][68];
    __shared__ __align__(16) float Bs[BK][68];

    const int tid  = threadIdx.x;
    const int tx   = tid & 15;
    const int ty   = tid >> 4;
    const int pix0 = blockIdx.x * 64;
    const int co0  = blockIdx.y * 64;

    const int a_co = tid >> 2;
    const int a_k4 = (tid & 3) * 4;
    const int b_p  = tid & 63;
    const int b_kr = tid >> 6;

    const int gp = pix0 + b_p;
    const int pb = gp / HW;
    const int pr = gp - pb * HW;
    const int py = pr / W;
    const int px = pr - py * W;
    const float* inb = in + (size_t)pb * (CIN * HW);

    float acc[4][4];
#pragma unroll
    for (int i = 0; i < 4; ++i)
#pragma unroll
        for (int j = 0; j < 4; ++j) acc[i][j] = 0.f;

    constexpr int kIters = (K + BK - 1) / BK;
    for (int it = 0; it < kIters; ++it) {
        const int kb = it * BK;
#pragma unroll
        for (int i = 0; i < 4; ++i) {
            const int k = kb + a_k4 + i;
            As[a_k4 + i][a_co] = (k < K) ? wgt[(size_t)(co0 + a_co) * K + k] : 0.f;
        }
#pragma unroll
        for (int i = 0; i < 4; ++i) {
            const int kl = b_kr + i * 4;
            const int gk = kb + kl;
            float v = 0.f;
            if (gk < K) {
                const int ci = gk / 9;
                const int r9 = gk - ci * 9;
                const int ky = r9 / 3;
                const int kx = r9 - ky * 3;
                const int iy = py + ky - 1;
                const int ix = px + kx - 1;
                if ((unsigned)iy < (unsigned)H && (unsigned)ix < (unsigned)W)
                    v = inb[(size_t)ci * HW + iy * W + ix];
            }
            Bs[kl][b_p] = v;
        }
        __syncthreads();
#pragma unroll
        for (int kk = 0; kk < BK; ++kk) {
            const float4 av = *reinterpret_cast<const float4*>(&As[kk][ty * 4]);
            const float4 bv = *reinterpret_cast<const float4*>(&Bs[kk][tx * 4]);
            const float a0[4] = {av.x, av.y, av.z, av.w};
            const float b0[4] = {bv.x, bv.y, bv.z, bv.w};
#pragma unroll
            for (int i = 0; i < 4; ++i)
#pragma unroll
                for (int j = 0; j < 4; ++j)
                    acc[i][j] += a0[i] * b0[j];
        }
        __syncthreads();
    }

    const int p0  = pix0 + tx * 4;
    const int ob  = p0 / HW;
    const int orr = p0 - ob * HW;
    const int oy  = orr / W;
    const int ox  = orr - oy * W;

#pragma unroll
    for (int i = 0; i < 4; ++i) {
        const int co = co0 + ty * 4 + i;
        float4 v = make_float4(acc[i][0], acc[i][1], acc[i][2], acc[i][3]);
        if (BIAS_RELU) {
            const float bv = bias[co];
            v.x = fmaxf(v.x + bv, 0.f);
            v.y = fmaxf(v.y + bv, 0.f);
            v.z = fmaxf(v.z + bv, 0.f);
            v.w = fmaxf(v.w + bv, 0.f);
        }
        *reinterpret_cast<float4*>(&out[((size_t)(ob * COUT + co)) * HW + oy * W + ox]) = v;
    }
}

// ---------------- BN batch statistics --------------------------------------
template <int C, int HW>
__global__ __launch_bounds__(256)
void bn_stats_kernel(const float* __restrict__ in, float* __restrict__ sums, int B)
{
    const int c  = blockIdx.x;
    const int nb = blockIdx.y;
    const int total = B * HW;
    const int chunk = total / 64;
    float s = 0.f, s2 = 0.f;
    for (int e = nb * chunk + threadIdx.x; e < (nb + 1) * chunk; e += 256) {
        const int b  = e / HW;
        const int spp = e & (HW - 1);
        const float v = in[((size_t)(b * C + c)) * HW + spp];
        s += v; s2 += v * v;
    }
#pragma unroll
    for (int off = 32; off > 0; off >>= 1) {
        s  += __shfl_down(s, off);
        s2 += __shfl_down(s2, off);
    }
    __shared__ float red[8];
    const int wid = threadIdx.x >> 6;
    if ((threadIdx.x & 63) == 0) { red[wid] = s; red[4 + wid] = s2; }
    __syncthreads();
    if (threadIdx.x == 0) {
        atomicAdd(&sums[c],     red[0] + red[1] + red[2] + red[3]);
        atomicAdd(&sums[C + c], red[4] + red[5] + red[6] + red[7]);
    }
}

template <int C>
__global__ void bn_finalize_kernel(const float* __restrict__ sums,
                                   const float* __restrict__ g,
                                   const float* __restrict__ beta,
                                   float* __restrict__ ss, int Ntot)
{
    const int c = blockIdx.x * 64 + threadIdx.x;
    if (c >= C) return;
    const float inv   = 1.f / (float)Ntot;
    const float mean  = sums[c] * inv;
    const float var   = sums[C + c] * inv - mean * mean;
    const float scale = g[c] * rsqrtf(var + BN_EPS);
    ss[c]     = scale;
    ss[C + c] = beta[c] - mean * scale;
}

// ---------------- maxpool k3 s2 p1 (opt fused BN+ReLU) ---------------------
template <int C, int Hin, int Win, bool DO_BN>
__global__ __launch_bounds__(256)
void maxpool_kernel(const float* __restrict__ in, const float* __restrict__ ss,
                    float* __restrict__ out, int B)
{
    constexpr int Ho = Hin / 2, Wo = Win / 2;
    const int t = blockIdx.x * 256 + threadIdx.x;
    const int total = B * C * Ho * Wo;
    if (t >= total) return;
    const int ox = t % Wo;
    const int oy = (t / Wo) % Ho;
    const int c  = (t / (Wo * Ho)) % C;
    const int b  = t / (Wo * Ho * C);
    float scale = 1.f, shift = 0.f;
    if (DO_BN) { scale = ss[c]; shift = ss[C + c]; }
    const float* ip = in + ((size_t)(b * C + c)) * (Hin * Win);
    const int y0 = max(0, 2 * oy - 1), y1 = min(Hin - 1, 2 * oy + 1);
    const int x0 = max(0, 2 * ox - 1), x1 = min(Win - 1, 2 * ox + 1);
    float m = -1e30f;
    for (int iy = y0; iy <= y1; ++iy)
        for (int ix = x0; ix <= x1; ++ix) {
            float v = ip[iy * Win + ix];
            if (DO_BN) v = v * scale + shift;
            m = fmaxf(m, v);
        }
    if (DO_BN) m = fmaxf(m, 0.f);
    out[t] = m;
}

// ---------------- conv7 partial-sum + bias + relu -> feats part of X -------
__global__ __launch_bounds__(256)
void build_x_feats_kernel(const float* __restrict__ part, const float* __restrict__ bias,
                          float* __restrict__ X, int B)
{
    const int t = blockIdx.x * 256 + threadIdx.x;
    if (t >= B * 512) return;
    const int b = t >> 9;
    const int c = t & 511;
    const size_t S = (size_t)B * 512 * 16;
    const float* p0 = part + ((size_t)(b * 512 + c)) * 16;
    float v[16];
#pragma unroll
    for (int qv = 0; qv < 16; ++qv) v[qv] = 0.f;
#pragma unroll
    for (int z = 0; z < 4; ++z) {
        const float* pz = p0 + z * S;
#pragma unroll
        for (int qv = 0; qv < 4; ++qv) {
            const float4 f = *reinterpret_cast<const float4*>(&pz[qv * 4]);
            v[qv * 4 + 0] += f.x;
            v[qv * 4 + 1] += f.y;
            v[qv * 4 + 2] += f.z;
            v[qv * 4 + 3] += f.w;
        }
    }
    const float bb = bias[c];
#pragma unroll
    for (int n = 0; n < 16; ++n) {
        const float r = fmaxf(v[n] + bb, 0.f);
        X[((size_t)(n * B + b)) * 592 + 80 + c] = r;
    }
}

// ---------------- colons fc1 (fp32) ----------------------------------------
__global__ __launch_bounds__(256)
void colon_fc1_kernel(const float* __restrict__ X, const float* __restrict__ W1,
                      const float* __restrict__ b1, float* __restrict__ h, int B)
{
    constexpr int N = 600, K = 592, BK = 16;
    const int n  = blockIdx.z;
    const int m0 = blockIdx.y * 64;
    const int o0 = blockIdx.x * 64;

    __shared__ __align__(16) float As[BK][68];
    __shared__ __align__(16) float Bs[BK][68];

    const int tid = threadIdx.x;
    const int tx = tid & 15, ty = tid >> 4;
    const int a_m = tid >> 2, a_k4 = (tid & 3) * 4;
    const int b_o = tid & 63, b_kr = tid >> 6;

    const float* Xn  = X  + (size_t)n * B * K;
    const float* W1n = W1 + (size_t)n * K * N;

    float acc[4][4];
#pragma unroll
    for (int i = 0; i < 4; ++i)
#pragma unroll
        for (int j = 0; j < 4; ++j) acc[i][j] = 0.f;

    for (int kb = 0; kb < K; kb += BK) {
        const float4 av = *reinterpret_cast<const float4*>(
            &Xn[(size_t)(m0 + a_m) * K + kb + a_k4]);
        As[a_k4 + 0][a_m] = av.x;
        As[a_k4 + 1][a_m] = av.y;
        As[a_k4 + 2][a_m] = av.z;
        As[a_k4 + 3][a_m] = av.w;
#pragma unroll
        for (int i = 0; i < 4; ++i) {
            const int kl = b_kr + i * 4;
            const int o  = o0 + b_o;
            Bs[kl][b_o] = (o < N) ? W1n[(size_t)(kb + kl) * N + o] : 0.f;
        }
        __syncthreads();
#pragma unroll
        for (int kk = 0; kk < BK; ++kk) {
            const float4 a4 = *reinterpret_cast<const float4*>(&As[kk][ty * 4]);
            const float4 b4 = *reinterpret_cast<const float4*>(&Bs[kk][tx * 4]);
            const float a0[4] = {a4.x, a4.y, a4.z, a4.w};
            const float b0[4] = {b4.x, b4.y, b4.z, b4.w};
#pragma unroll
            for (int i = 0; i < 4; ++i)
#pragma unroll
                for (int j = 0; j < 4; ++j)
                    acc[i][j] += a0[i] * b0[j];
        }
        __syncthreads();
    }

#pragma unroll
    for (int i = 0; i < 4; ++i) {
        const int m = m0 + ty * 4 + i;
#pragma unroll
        for (int j = 0; j < 4; ++j) {
            const int o = o0 + tx * 4 + j;
            if (o < N)
                h[((size_t)(n * B + m)) * N + o] = tanhf(acc[i][j] + b1[n * N + o]);
        }
    }
}

// ---------------- colons fc2 + softmax -------------------------------------
__global__ __launch_bounds__(128)
void colon_fc2_kernel(const float* __restrict__ h, const float* __restrict__ W2,
                      const float* __restrict__ b2, float* __restrict__ preds, int B)
{
    const int n = blockIdx.x;
    __shared__ float W2s[6000];
    __shared__ float b2s[10];
    for (int i = threadIdx.x; i < 6000; i += 128) W2s[i] = W2[n * 6000 + i];
    if (threadIdx.x < 10) b2s[threadIdx.x] = b2[n * 10 + threadIdx.x];
    __syncthreads();

    for (int b = threadIdx.x; b < B; b += 128) {
        float l[10];
#pragma unroll
        for (int c = 0; c < 10; ++c) l[c] = b2s[c];
        const float* hp = h + ((size_t)(n * B + b)) * 600;
        for (int k = 0; k < 600; k += 4) {
            const float4 hv = *reinterpret_cast<const float4*>(&hp[k]);
            const float hh[4] = {hv.x, hv.y, hv.z, hv.w};
#pragma unroll
            for (int u = 0; u < 4; ++u)
#pragma unroll
                for (int c = 0; c < 10; ++c)
                    l[c] += hh[u] * W2s[(k + u) * 10 + c];
        }
        float mx = l[0];
#pragma unroll
        for (int c = 1; c < 10; ++c) mx = fmaxf(mx, l[c]);
        float s = 0.f;
#pragma unroll
        for (int c = 0; c < 10; ++c) { l[c] = expf(l[c] - mx); s += l[c]; }
        const float inv = 1.f / s;
        float* pp = preds + ((size_t)(n * B + b)) * 10;
#pragma unroll
        for (int c = 0; c < 10; ++c) pp[c] = l[c] * inv;
    }
}

// ---------------- neighbor gather ------------------------------------------
__global__ __launch_bounds__(256)
void fill_neigh_kernel(const float* __restrict__ preds1, float* __restrict__ X, int B)
{
    const int t = blockIdx.x * 256 + threadIdx.x;
    if (t >= 16 * B * 80) return;
    const int c = t % 10;
    const int j = (t / 10) & 7;
    const int b = (t / 80) % B;
    const int n = t / (80 * B);

    int lst[8];
    int cnt = 0;
    const int w = 4, sz = 16, i = n;
    if (i - w >= 0)                                lst[cnt++] = i - w;
    if (i % w != 0)                                lst[cnt++] = i - 1;
    if ((i + 1) % w != 0)                          lst[cnt++] = i + 1;
    if (i + w < sz)                                lst[cnt++] = i + w;
    if (i - w - 1 >= 0 && i % w != 0)              lst[cnt++] = i - w - 1;
    if (i - w + 1 >= 0 && (i + 1) % w != 0)        lst[cnt++] = i - w + 1;
    if (i + w - 1 < sz && i % w != 0)              lst[cnt++] = i + w - 1;
    if (i + w + 1 < sz && (i + 1) % w != 0)        lst[cnt++] = i + w + 1;

    float v = 0.f;
    if (j < cnt) v = preds1[((size_t)(lst[j] * B + b)) * 10 + c];
    X[((size_t)(n * B + b)) * 592 + j * 10 + c] = v;
}

// ---------------- final ----------------------------------------------------
__global__ __launch_bounds__(256)
void final_out_kernel(const float* __restrict__ preds2, float* __restrict__ out0, int B)
{
    const int t = blockIdx.x * 256 + threadIdx.x;
    if (t >= B * 10) return;
    const int b = t / 10, c = t % 10;
    float s = 0.f;
#pragma unroll
    for (int n = 0; n < 16; ++n)
        s += preds2[((size_t)(n * B + b)) * 10 + c];
    const float m = s * (1.f / 16.f);
    out0[t] = m * m;
}

// ---------------------------------------------------------------------------
extern "C" void kernel_launch(void* const* d_in, const int* in_sizes, int n_in,
                              void* d_out, int out_size, void* d_ws, size_t ws_size,
                              hipStream_t stream)
{
    const float* x    = (const float*)d_in[0];
    const float* cw1  = (const float*)d_in[1];
    const float* bn1g = (const float*)d_in[3];
    const float* bn1b = (const float*)d_in[4];
    const float* cw2  = (const float*)d_in[5];
    const float* bn2g = (const float*)d_in[7];
    const float* bn2b = (const float*)d_in[8];
    const float* cw3  = (const float*)d_in[9];
    const float* cb3  = (const float*)d_in[10];
    const float* cw4  = (const float*)d_in[11];
    const float* cb4  = (const float*)d_in[12];
    const float* cw5  = (const float*)d_in[13];
    const float* cb5  = (const float*)d_in[14];
    const float* cw6  = (const float*)d_in[15];
    const float* cb6  = (const float*)d_in[16];
    const float* cw7  = (const float*)d_in[17];
    const float* cb7  = (const float*)d_in[18];
    const float* W1   = (const float*)d_in[19];
    const float* b1   = (const float*)d_in[20];
    const float* W2   = (const float*)d_in[21];
    const float* b2   = (const float*)d_in[22];

    const int B = in_sizes[0] / (3 * 64 * 64);   // 128

    // ---- workspace layout (floats) ----
    float* ws    = (float*)d_ws;
    float* buf0  = ws;                       // 33.5M floats
    float* buf1  = ws + 33554432;            // 16.7M floats (first ~8.4M hot)
    float* small = ws + 50331648;
    float* sums1  = small;
    float* sums2  = small + 256;
    float* ss1    = small + 1024;
    float* ss2    = small + 1536;
    float* preds1 = small + 2048;
    float* Xb     = buf1 + 2097152;
    float* hb     = buf0 + 8388608;

    // f16 transformed weights live in buf1 tail (buf1 writes never exceed 8.4M floats)
    _Float16* w9 = (_Float16*)(buf1 + 9437184);
    _Float16* w9c2 = w9;
    _Float16* w9c3 = w9 + 73728;
    _Float16* w9c4 = w9 + 368640;
    _Float16* w9c5 = w9 + 958464;
    _Float16* w9c6 = w9 + 2138112;
    _Float16* w9c7 = w9 + 4497408;

    float* out0   = (float*)d_out;
    float* preds2 = (float*)d_out + (size_t)B * 10;

    hipMemsetAsync(small, 0, 512 * sizeof(float), stream);

    // ---- weight pre-transforms (f16 [9][CO*CI]) ----
    wsplit_kernel<<<(128 * 64   + 255) / 256, 256, 0, stream>>>(cw2, w9c2, 128 * 64);
    wsplit_kernel<<<(256 * 128  + 255) / 256, 256, 0, stream>>>(cw3, w9c3, 256 * 128);
    wsplit_kernel<<<(256 * 256  + 255) / 256, 256, 0, stream>>>(cw4, w9c4, 256 * 256);
    wsplit_kernel<<<(512 * 256  + 255) / 256, 256, 0, stream>>>(cw5, w9c5, 512 * 256);
    wsplit_kernel<<<(512 * 512  + 255) / 256, 256, 0, stream>>>(cw6, w9c6, 512 * 512);
    wsplit_kernel<<<(512 * 512  + 255) / 256, 256, 0, stream>>>(cw7, w9c7, 512 * 512);

    // ---- backbone ----
    conv3x3_kernel<3, 64, 64, 64, 1, false>
        <<<dim3(B * 4096 / 64, 1, 1), 256, 0, stream>>>(x, cw1, nullptr, buf0, B);
    bn_stats_kernel<64, 4096><<<dim3(64, 64), 256, 0, stream>>>(buf0, sums1, B);
    bn_finalize_kernel<64><<<1, 64, 0, stream>>>(sums1, bn1g, bn1b, ss1, B * 4096);
    maxpool_kernel<64, 64, 64, true>
        <<<(B * 64 * 32 * 32 + 255) / 256, 256, 0, stream>>>(buf0, ss1, buf1, B);

    // conv2: 64->128 @32x32 (MFMA), BN absorbs bias
    conv_mfma_kernel<64, 128, 32, 32, 1, false>
        <<<dim3(B * 1024 / 128, 1, 1), 256, 0, stream>>>(buf1, w9c2, nullptr, buf0, B);
    bn_stats_kernel<128, 1024><<<dim3(128, 64), 256, 0, stream>>>(buf0, sums2, B);
    bn_finalize_kernel<128><<<2, 64, 0, stream>>>(sums2, bn2g, bn2b, ss2, B * 1024);
    maxpool_kernel<128, 32, 32, true>
        <<<(B * 128 * 16 * 16 + 255) / 256, 256, 0, stream>>>(buf0, ss2, buf1, B);

    // conv3: 128->256 @16x16
    conv_mfma_kernel<128, 256, 16, 16, 1, true>
        <<<dim3(B * 256 / 128, 2, 1), 256, 0, stream>>>(buf1, w9c3, cb3, buf0, B);
    // conv4: 256->256 @16x16 + pool
    conv_mfma_kernel<256, 256, 16, 16, 1, true>
        <<<dim3(B * 256 / 128, 2, 1), 256, 0, stream>>>(buf0, w9c4, cb4, buf1, B);
    maxpool_kernel<256, 16, 16, false>
        <<<(B * 256 * 8 * 8 + 255) / 256, 256, 0, stream>>>(buf1, nullptr, buf0, B);

    // conv5: 256->512 @8x8
    conv_mfma_kernel<256, 512, 8, 8, 1, true>
        <<<dim3(B * 64 / 128, 4, 1), 256, 0, stream>>>(buf0, w9c5, cb5, buf1, B);
    // conv6: 512->512 @8x8 + pool
    conv_mfma_kernel<512, 512, 8, 8, 1, true>
        <<<dim3(B * 64 / 128, 4, 1), 256, 0, stream>>>(buf1, w9c6, cb6, buf0, B);
    maxpool_kernel<512, 8, 8, false>
        <<<(B * 512 * 4 * 4 + 255) / 256, 256, 0, stream>>>(buf0, nullptr, buf1, B);

    // conv7: 512->512 @4x4, split-K=4 partials
    conv_mfma_kernel<512, 512, 4, 4, 4, false>
        <<<dim3(B * 16 / 128, 4, 4), 256, 0, stream>>>(buf1, w9c7, nullptr, buf0, B);

    // ---- colons ----
    hipMemsetAsync(Xb, 0, (size_t)16 * B * 592 * sizeof(float), stream);
    build_x_feats_kernel<<<(B * 512 + 255) / 256, 256, 0, stream>>>(buf0, cb7, Xb, B);

    colon_fc1_kernel<<<dim3(10, B / 64, 16), 256, 0, stream>>>(Xb, W1, b1, hb, B);
    colon_fc2_kernel<<<16, 128, 0, stream>>>(hb, W2, b2, preds1, B);

    fill_neigh_kernel<<<(16 * B * 80 + 255) / 256, 256, 0, stream>>>(preds1, Xb, B);
    colon_fc1_kernel<<<dim3(10, B / 64, 16), 256, 0, stream>>>(Xb, W1, b1, hb, B);
    colon_fc2_kernel<<<16, 128, 0, stream>>>(hb, W2, b2, preds2, B);

    final_out_kernel<<<(B * 10 + 255) / 256, 256, 0, stream>>>(preds2, out0, B);
}

// Round 3
// 964.021 us; speedup vs baseline: 3.1570x; 1.1225x over previous
//
#include <hip/hip_runtime.h>
#include <math.h>

// ---------------------------------------------------------------------------
// Brain_49374944035335  R3: split-K on conv5/6/7 (grid 256 -> 1024/512 blocks,
// fixes 1-block/CU latency bind seen in R2: MfmaUtil 10%, Occ 11%), partials
// reduced by elementwise sum_bias_relu. fc1 dedup: pre = feats.W1[80:]+b1
// computed once; pass2 adds only the K=80 neighbor GEMM.
// ---------------------------------------------------------------------------

#define BN_EPS 1e-5f

typedef _Float16 f16x8 __attribute__((ext_vector_type(8)));
typedef float    f32x4v __attribute__((ext_vector_type(4)));

constexpr int ilog2c(int x) { return x <= 1 ? 0 : 1 + ilog2c(x >> 1); }

// ---------------- weight pre-transform: OIHW fp32 -> [9][CO*CI] f16 --------
__global__ __launch_bounds__(256)
void wsplit_kernel(const float* __restrict__ w, _Float16* __restrict__ o, int COCI)
{
    const int t = blockIdx.x * 256 + threadIdx.x;
    if (t >= COCI) return;
#pragma unroll
    for (int ph = 0; ph < 9; ++ph)
        o[ph * COCI + t] = (_Float16)w[t * 9 + ph];
}

// ---------------- MFMA conv: 3x3 SAME as 9 shifted GEMMs -------------------
template <int CI, int CO, int H, int W, int KSPLIT, bool BIAS_RELU>
__global__ __launch_bounds__(256)
void conv_mfma_kernel(const float* __restrict__ in, const _Float16* __restrict__ w9,
                      const float* __restrict__ bias, float* __restrict__ out, int B)
{
    constexpr int HW   = H * W;
    constexpr int lgHW = ilog2c(HW);
    constexpr int lgW  = ilog2c(W);

    __shared__ _Float16 As[128 * 32];
    __shared__ _Float16 Bs[128 * 32];

    const int tid  = threadIdx.x;
    const int pix0 = blockIdx.x * 128;
    const int co0  = blockIdx.y * 128;

    const int bn = tid & 127;
    const int bh = tid >> 7;
    const int gp = pix0 + bn;
    const int pb = gp >> lgHW;
    const int sp = gp & (HW - 1);
    const int py = sp >> lgW;
    const int px = sp & (W - 1);
    const float* inb = in + ((size_t)(pb * CI) << lgHW);

    const int arow = tid >> 1;
    const int acl  = (tid & 1) * 16;

    const int lane = tid & 63;
    const int wv   = tid >> 6;
    const int wm   = (wv & 1) * 64;
    const int wn   = (wv >> 1) * 64;
    const int q    = lane >> 4;
    const int lm   = lane & 15;
    const int bsw  = (q ^ (lm & 3)) << 3;

    f32x4v acc[4][4];
#pragma unroll
    for (int i = 0; i < 4; ++i)
#pragma unroll
        for (int j = 0; j < 4; ++j) acc[i][j] = (f32x4v)0.f;

    constexpr int CS_TOT = CI / 32;
    constexpr int CS_PER = CS_TOT / KSPLIT;
    const int cs0 = (KSPLIT > 1) ? blockIdx.z * CS_PER : 0;

    for (int ph = 0; ph < 9; ++ph) {
        const int dy = ph / 3 - 1;
        const int dx = ph - (ph / 3) * 3 - 1;
        const int y2 = py + dy;
        const int x2 = px + dx;
        const bool valid = ((unsigned)y2 < (unsigned)H) && ((unsigned)x2 < (unsigned)W);
        const float msk = valid ? 1.f : 0.f;
        const int off = valid ? ((y2 << lgW) + x2) : 0;
        const float* bsrc = inb + ((size_t)(bh * 16) << lgHW) + off;
        const _Float16* asrc = w9 + ((size_t)(ph * CO + co0 + arow)) * CI + acl;

        for (int cs = cs0; cs < cs0 + CS_PER; ++cs) {
            const f16x8 a0 = *(const f16x8*)(asrc + cs * 32);
            const f16x8 a1 = *(const f16x8*)(asrc + cs * 32 + 8);
            float bv[16];
            const float* bp = bsrc + ((size_t)(cs * 32) << lgHW);
#pragma unroll
            for (int u = 0; u < 16; ++u) bv[u] = bp[(size_t)u << lgHW];

            __syncthreads();
            *(f16x8*)&As[arow * 32 + acl]     = a0;
            *(f16x8*)&As[arow * 32 + acl + 8] = a1;
            f16x8 p0, p1;
#pragma unroll
            for (int u = 0; u < 8; ++u) p0[u] = (_Float16)(bv[u] * msk);
#pragma unroll
            for (int u = 0; u < 8; ++u) p1[u] = (_Float16)(bv[8 + u] * msk);
            const int o0 = ((2 * bh) ^ (bn & 3)) << 3;
            const int o1 = ((2 * bh + 1) ^ (bn & 3)) << 3;
            *(f16x8*)&Bs[bn * 32 + o0] = p0;
            *(f16x8*)&Bs[bn * 32 + o1] = p1;
            __syncthreads();

            f16x8 af[4], bf[4];
#pragma unroll
            for (int ti = 0; ti < 4; ++ti)
                af[ti] = *(const f16x8*)&As[(wm + ti * 16 + lm) * 32 + (q << 3)];
#pragma unroll
            for (int tj = 0; tj < 4; ++tj)
                bf[tj] = *(const f16x8*)&Bs[(wn + tj * 16 + lm) * 32 + bsw];
#pragma unroll
            for (int ti = 0; ti < 4; ++ti)
#pragma unroll
                for (int tj = 0; tj < 4; ++tj)
                    acc[ti][tj] = __builtin_amdgcn_mfma_f32_16x16x32_f16(
                        af[ti], bf[tj], acc[ti][tj], 0, 0, 0);
        }
    }

    float* outz = out;
    if (KSPLIT > 1) outz += (size_t)blockIdx.z * B * CO * HW;

#pragma unroll
    for (int tj = 0; tj < 4; ++tj) {
        const int gpix = pix0 + wn + tj * 16 + lm;
        const int opb  = gpix >> lgHW;
        const int osp  = gpix & (HW - 1);
#pragma unroll
        for (int ti = 0; ti < 4; ++ti) {
            const int cob = co0 + wm + ti * 16 + q * 4;
#pragma unroll
            for (int r = 0; r < 4; ++r) {
                float v = acc[ti][tj][r];
                if (BIAS_RELU) v = fmaxf(v + bias[cob + r], 0.f);
                outz[((size_t)(opb * CO + cob + r) << lgHW) + osp] = v;
            }
        }
    }
}

// ---------------- split-K partial reduce: out = relu(sum_z part_z + bias) --
template <int CO, int HW, int Z>
__global__ __launch_bounds__(256)
void sum_bias_relu_kernel(const float* __restrict__ part, const float* __restrict__ bias,
                          float* __restrict__ out, int B)
{
    const int t = blockIdx.x * 256 + threadIdx.x;
    const int N4 = B * CO * HW / 4;
    if (t >= N4) return;
    const size_t S = (size_t)B * CO * HW;
    const int i4 = t * 4;
    const int c  = (i4 >> ilog2c(HW)) & (CO - 1);
    float4 a = *(const float4*)(part + i4);
#pragma unroll
    for (int z = 1; z < Z; ++z) {
        const float4 p = *(const float4*)(part + (size_t)z * S + i4);
        a.x += p.x; a.y += p.y; a.z += p.z; a.w += p.w;
    }
    const float bb = bias[c];
    a.x = fmaxf(a.x + bb, 0.f);
    a.y = fmaxf(a.y + bb, 0.f);
    a.z = fmaxf(a.z + bb, 0.f);
    a.w = fmaxf(a.w + bb, 0.f);
    *(float4*)(out + i4) = a;
}

// ---------------- fp32 conv (conv1 only, K=27) -----------------------------
template <int CIN, int COUT, int H, int W, int KSPLIT, bool BIAS_RELU>
__global__ __launch_bounds__(256)
void conv3x3_kernel(const float* __restrict__ in, const float* __restrict__ wgt,
                    const float* __restrict__ bias, float* __restrict__ out, int B)
{
    constexpr int K  = CIN * 9;
    constexpr int HW = H * W;
    constexpr int BK = 16;

    __shared__ __align__(16) float As[BK][68];
    __shared__ __align__(16) float Bs[BK][68];

    const int tid  = threadIdx.x;
    const int tx   = tid & 15;
    const int ty   = tid >> 4;
    const int pix0 = blockIdx.x * 64;
    const int co0  = blockIdx.y * 64;

    const int a_co = tid >> 2;
    const int a_k4 = (tid & 3) * 4;
    const int b_p  = tid & 63;
    const int b_kr = tid >> 6;

    const int gp = pix0 + b_p;
    const int pb = gp / HW;
    const int pr = gp - pb * HW;
    const int py = pr / W;
    const int px = pr - py * W;
    const float* inb = in + (size_t)pb * (CIN * HW);

    float acc[4][4];
#pragma unroll
    for (int i = 0; i < 4; ++i)
#pragma unroll
        for (int j = 0; j < 4; ++j) acc[i][j] = 0.f;

    constexpr int kIters = (K + BK - 1) / BK;
    for (int it = 0; it < kIters; ++it) {
        const int kb = it * BK;
#pragma unroll
        for (int i = 0; i < 4; ++i) {
            const int k = kb + a_k4 + i;
            As[a_k4 + i][a_co] = (k < K) ? wgt[(size_t)(co0 + a_co) * K + k] : 0.f;
        }
#pragma unroll
        for (int i = 0; i < 4; ++i) {
            const int kl = b_kr + i * 4;
            const int gk = kb + kl;
            float v = 0.f;
            if (gk < K) {
                const int ci = gk / 9;
                const int r9 = gk - ci * 9;
                const int ky = r9 / 3;
                const int kx = r9 - ky * 3;
                const int iy = py + ky - 1;
                const int ix = px + kx - 1;
                if ((unsigned)iy < (unsigned)H && (unsigned)ix < (unsigned)W)
                    v = inb[(size_t)ci * HW + iy * W + ix];
            }
            Bs[kl][b_p] = v;
        }
        __syncthreads();
#pragma unroll
        for (int kk = 0; kk < BK; ++kk) {
            const float4 av = *reinterpret_cast<const float4*>(&As[kk][ty * 4]);
            const float4 bv = *reinterpret_cast<const float4*>(&Bs[kk][tx * 4]);
            const float a0[4] = {av.x, av.y, av.z, av.w};
            const float b0[4] = {bv.x, bv.y, bv.z, bv.w};
#pragma unroll
            for (int i = 0; i < 4; ++i)
#pragma unroll
                for (int j = 0; j < 4; ++j)
                    acc[i][j] += a0[i] * b0[j];
        }
        __syncthreads();
    }

    const int p0  = pix0 + tx * 4;
    const int ob  = p0 / HW;
    const int orr = p0 - ob * HW;
    const int oy  = orr / W;
    const int ox  = orr - oy * W;

#pragma unroll
    for (int i = 0; i < 4; ++i) {
        const int co = co0 + ty * 4 + i;
        float4 v = make_float4(acc[i][0], acc[i][1], acc[i][2], acc[i][3]);
        if (BIAS_RELU) {
            const float bv = bias[co];
            v.x = fmaxf(v.x + bv, 0.f);
            v.y = fmaxf(v.y + bv, 0.f);
            v.z = fmaxf(v.z + bv, 0.f);
            v.w = fmaxf(v.w + bv, 0.f);
        }
        *reinterpret_cast<float4*>(&out[((size_t)(ob * COUT + co)) * HW + oy * W + ox]) = v;
    }
}

// ---------------- BN batch statistics --------------------------------------
template <int C, int HW>
__global__ __launch_bounds__(256)
void bn_stats_kernel(const float* __restrict__ in, float* __restrict__ sums, int B)
{
    const int c  = blockIdx.x;
    const int nb = blockIdx.y;
    const int total = B * HW;
    const int chunk = total / 64;
    float s = 0.f, s2 = 0.f;
    for (int e = nb * chunk + threadIdx.x; e < (nb + 1) * chunk; e += 256) {
        const int b  = e / HW;
        const int spp = e & (HW - 1);
        const float v = in[((size_t)(b * C + c)) * HW + spp];
        s += v; s2 += v * v;
    }
#pragma unroll
    for (int off = 32; off > 0; off >>= 1) {
        s  += __shfl_down(s, off);
        s2 += __shfl_down(s2, off);
    }
    __shared__ float red[8];
    const int wid = threadIdx.x >> 6;
    if ((threadIdx.x & 63) == 0) { red[wid] = s; red[4 + wid] = s2; }
    __syncthreads();
    if (threadIdx.x == 0) {
        atomicAdd(&sums[c],     red[0] + red[1] + red[2] + red[3]);
        atomicAdd(&sums[C + c], red[4] + red[5] + red[6] + red[7]);
    }
}

template <int C>
__global__ void bn_finalize_kernel(const float* __restrict__ sums,
                                   const float* __restrict__ g,
                                   const float* __restrict__ beta,
                                   float* __restrict__ ss, int Ntot)
{
    const int c = blockIdx.x * 64 + threadIdx.x;
    if (c >= C) return;
    const float inv   = 1.f / (float)Ntot;
    const float mean  = sums[c] * inv;
    const float var   = sums[C + c] * inv - mean * mean;
    const float scale = g[c] * rsqrtf(var + BN_EPS);
    ss[c]     = scale;
    ss[C + c] = beta[c] - mean * scale;
}

// ---------------- maxpool k3 s2 p1 (opt fused BN+ReLU) ---------------------
template <int C, int Hin, int Win, bool DO_BN>
__global__ __launch_bounds__(256)
void maxpool_kernel(const float* __restrict__ in, const float* __restrict__ ss,
                    float* __restrict__ out, int B)
{
    constexpr int Ho = Hin / 2, Wo = Win / 2;
    const int t = blockIdx.x * 256 + threadIdx.x;
    const int total = B * C * Ho * Wo;
    if (t >= total) return;
    const int ox = t % Wo;
    const int oy = (t / Wo) % Ho;
    const int c  = (t / (Wo * Ho)) % C;
    const int b  = t / (Wo * Ho * C);
    float scale = 1.f, shift = 0.f;
    if (DO_BN) { scale = ss[c]; shift = ss[C + c]; }
    const float* ip = in + ((size_t)(b * C + c)) * (Hin * Win);
    const int y0 = max(0, 2 * oy - 1), y1 = min(Hin - 1, 2 * oy + 1);
    const int x0 = max(0, 2 * ox - 1), x1 = min(Win - 1, 2 * ox + 1);
    float m = -1e30f;
    for (int iy = y0; iy <= y1; ++iy)
        for (int ix = x0; ix <= x1; ++ix) {
            float v = ip[iy * Win + ix];
            if (DO_BN) v = v * scale + shift;
            m = fmaxf(m, v);
        }
    if (DO_BN) m = fmaxf(m, 0.f);
    out[t] = m;
}

// ---------------- conv7 partial-sum + bias + relu -> feats part of X -------
template <int Z>
__global__ __launch_bounds__(256)
void build_x_feats_kernel(const float* __restrict__ part, const float* __restrict__ bias,
                          float* __restrict__ X, int B)
{
    const int t = blockIdx.x * 256 + threadIdx.x;
    if (t >= B * 512) return;
    const int b = t >> 9;
    const int c = t & 511;
    const size_t S = (size_t)B * 512 * 16;
    const float* p0 = part + ((size_t)(b * 512 + c)) * 16;
    float v[16];
#pragma unroll
    for (int qv = 0; qv < 16; ++qv) v[qv] = 0.f;
#pragma unroll
    for (int z = 0; z < Z; ++z) {
        const float* pz = p0 + (size_t)z * S;
#pragma unroll
        for (int qv = 0; qv < 4; ++qv) {
            const float4 f = *reinterpret_cast<const float4*>(&pz[qv * 4]);
            v[qv * 4 + 0] += f.x;
            v[qv * 4 + 1] += f.y;
            v[qv * 4 + 2] += f.z;
            v[qv * 4 + 3] += f.w;
        }
    }
    const float bb = bias[c];
#pragma unroll
    for (int n = 0; n < 16; ++n) {
        const float r = fmaxf(v[n] + bb, 0.f);
        X[((size_t)(n * B + b)) * 592 + 80 + c] = r;
    }
}

// ---------------- colons fc1 (fp32, generic K / pre handling) --------------
// WRITE_PRE: store raw pre-activation (for pass-2 reuse). ADD_PRE: add stored
// pre instead of b1 (pass-2 K=80 neighbor delta).
template <int K, int XOFF, int WOFF, bool WRITE_PRE, bool ADD_PRE>
__global__ __launch_bounds__(256)
void colon_fc1_kernel(const float* __restrict__ X, const float* __restrict__ W1,
                      const float* __restrict__ b1, float* __restrict__ pre,
                      float* __restrict__ h, int B)
{
    constexpr int N = 600, BK = 16;
    const int n  = blockIdx.z;
    const int m0 = blockIdx.y * 64;
    const int o0 = blockIdx.x * 64;

    __shared__ __align__(16) float As[BK][68];
    __shared__ __align__(16) float Bs[BK][68];

    const int tid = threadIdx.x;
    const int tx = tid & 15, ty = tid >> 4;
    const int a_m = tid >> 2, a_k4 = (tid & 3) * 4;
    const int b_o = tid & 63, b_kr = tid >> 6;

    const float* Xn  = X  + (size_t)n * B * 592;
    const float* W1n = W1 + (size_t)n * 592 * N;

    float acc[4][4];
#pragma unroll
    for (int i = 0; i < 4; ++i)
#pragma unroll
        for (int j = 0; j < 4; ++j) acc[i][j] = 0.f;

    for (int kb = 0; kb < K; kb += BK) {
        const float4 av = *reinterpret_cast<const float4*>(
            &Xn[(size_t)(m0 + a_m) * 592 + XOFF + kb + a_k4]);
        As[a_k4 + 0][a_m] = av.x;
        As[a_k4 + 1][a_m] = av.y;
        As[a_k4 + 2][a_m] = av.z;
        As[a_k4 + 3][a_m] = av.w;
#pragma unroll
        for (int i = 0; i < 4; ++i) {
            const int kl = b_kr + i * 4;
            const int o  = o0 + b_o;
            Bs[kl][b_o] = (o < N) ? W1n[(size_t)(WOFF + kb + kl) * N + o] : 0.f;
        }
        __syncthreads();
#pragma unroll
        for (int kk = 0; kk < BK; ++kk) {
            const float4 a4 = *reinterpret_cast<const float4*>(&As[kk][ty * 4]);
            const float4 b4 = *reinterpret_cast<const float4*>(&Bs[kk][tx * 4]);
            const float a0[4] = {a4.x, a4.y, a4.z, a4.w};
            const float b0[4] = {b4.x, b4.y, b4.z, b4.w};
#pragma unroll
            for (int i = 0; i < 4; ++i)
#pragma unroll
                for (int j = 0; j < 4; ++j)
                    acc[i][j] += a0[i] * b0[j];
        }
        __syncthreads();
    }

#pragma unroll
    for (int i = 0; i < 4; ++i) {
        const int m = m0 + ty * 4 + i;
#pragma unroll
        for (int j = 0; j < 4; ++j) {
            const int o = o0 + tx * 4 + j;
            if (o < N) {
                const size_t oi = ((size_t)(n * B + m)) * N + o;
                float v = acc[i][j] + (ADD_PRE ? pre[oi] : b1[n * N + o]);
                if (WRITE_PRE) pre[oi] = v;
                h[oi] = tanhf(v);
            }
        }
    }
}

// ---------------- colons fc2 + softmax -------------------------------------
__global__ __launch_bounds__(128)
void colon_fc2_kernel(const float* __restrict__ h, const float* __restrict__ W2,
                      const float* __restrict__ b2, float* __restrict__ preds, int B)
{
    const int n = blockIdx.x;
    __shared__ float W2s[6000];
    __shared__ float b2s[10];
    for (int i = threadIdx.x; i < 6000; i += 128) W2s[i] = W2[n * 6000 + i];
    if (threadIdx.x < 10) b2s[threadIdx.x] = b2[n * 10 + threadIdx.x];
    __syncthreads();

    for (int b = threadIdx.x; b < B; b += 128) {
        float l[10];
#pragma unroll
        for (int c = 0; c < 10; ++c) l[c] = b2s[c];
        const float* hp = h + ((size_t)(n * B + b)) * 600;
        for (int k = 0; k < 600; k += 4) {
            const float4 hv = *reinterpret_cast<const float4*>(&hp[k]);
            const float hh[4] = {hv.x, hv.y, hv.z, hv.w};
#pragma unroll
            for (int u = 0; u < 4; ++u)
#pragma unroll
                for (int c = 0; c < 10; ++c)
                    l[c] += hh[u] * W2s[(k + u) * 10 + c];
        }
        float mx = l[0];
#pragma unroll
        for (int c = 1; c < 10; ++c) mx = fmaxf(mx, l[c]);
        float s = 0.f;
#pragma unroll
        for (int c = 0; c < 10; ++c) { l[c] = expf(l[c] - mx); s += l[c]; }
        const float inv = 1.f / s;
        float* pp = preds + ((size_t)(n * B + b)) * 10;
#pragma unroll
        for (int c = 0; c < 10; ++c) pp[c] = l[c] * inv;
    }
}

// ---------------- neighbor gather ------------------------------------------
__global__ __launch_bounds__(256)
void fill_neigh_kernel(const float* __restrict__ preds1, float* __restrict__ X, int B)
{
    const int t = blockIdx.x * 256 + threadIdx.x;
    if (t >= 16 * B * 80) return;
    const int c = t % 10;
    const int j = (t / 10) & 7;
    const int b = (t / 80) % B;
    const int n = t / (80 * B);

    int lst[8];
    int cnt = 0;
    const int w = 4, sz = 16, i = n;
    if (i - w >= 0)                                lst[cnt++] = i - w;
    if (i % w != 0)                                lst[cnt++] = i - 1;
    if ((i + 1) % w != 0)                          lst[cnt++] = i + 1;
    if (i + w < sz)                                lst[cnt++] = i + w;
    if (i - w - 1 >= 0 && i % w != 0)              lst[cnt++] = i - w - 1;
    if (i - w + 1 >= 0 && (i + 1) % w != 0)        lst[cnt++] = i - w + 1;
    if (i + w - 1 < sz && i % w != 0)              lst[cnt++] = i + w - 1;
    if (i + w + 1 < sz && (i + 1) % w != 0)        lst[cnt++] = i + w + 1;

    float v = 0.f;
    if (j < cnt) v = preds1[((size_t)(lst[j] * B + b)) * 10 + c];
    X[((size_t)(n * B + b)) * 592 + j * 10 + c] = v;
}

// ---------------- final ----------------------------------------------------
__global__ __launch_bounds__(256)
void final_out_kernel(const float* __restrict__ preds2, float* __restrict__ out0, int B)
{
    const int t = blockIdx.x * 256 + threadIdx.x;
    if (t >= B * 10) return;
    const int b = t / 10, c = t % 10;
    float s = 0.f;
#pragma unroll
    for (int n = 0; n < 16; ++n)
        s += preds2[((size_t)(n * B + b)) * 10 + c];
    const float m = s * (1.f / 16.f);
    out0[t] = m * m;
}

// ---------------------------------------------------------------------------
extern "C" void kernel_launch(void* const* d_in, const int* in_sizes, int n_in,
                              void* d_out, int out_size, void* d_ws, size_t ws_size,
                              hipStream_t stream)
{
    const float* x    = (const float*)d_in[0];
    const float* cw1  = (const float*)d_in[1];
    const float* bn1g = (const float*)d_in[3];
    const float* bn1b = (const float*)d_in[4];
    const float* cw2  = (const float*)d_in[5];
    const float* bn2g = (const float*)d_in[7];
    const float* bn2b = (const float*)d_in[8];
    const float* cw3  = (const float*)d_in[9];
    const float* cb3  = (const float*)d_in[10];
    const float* cw4  = (const float*)d_in[11];
    const float* cb4  = (const float*)d_in[12];
    const float* cw5  = (const float*)d_in[13];
    const float* cb5  = (const float*)d_in[14];
    const float* cw6  = (const float*)d_in[15];
    const float* cb6  = (const float*)d_in[16];
    const float* cw7  = (const float*)d_in[17];
    const float* cb7  = (const float*)d_in[18];
    const float* W1   = (const float*)d_in[19];
    const float* b1   = (const float*)d_in[20];
    const float* W2   = (const float*)d_in[21];
    const float* b2   = (const float*)d_in[22];

    const int B = in_sizes[0] / (3 * 64 * 64);   // 128

    // ---- workspace layout (floats) ----
    float* ws    = (float*)d_ws;
    float* buf0  = ws;                       // 33.5M floats
    float* buf1  = ws + 33554432;            // 16.7M floats
    float* small = ws + 50331648;
    float* sums1  = small;
    float* sums2  = small + 256;
    float* ss1    = small + 1024;
    float* ss2    = small + 1536;
    float* preds1 = small + 2048;
    float* Xb     = buf1 + 2097152;          // [16][B][592]
    float* hb     = buf0 + 8388608;          // [16][B][600]
    float* preb   = buf0 + 10485760;         // [16][B][600]

    // f16 weights in buf1 tail (buf1 live writes stay < 9.4M floats)
    _Float16* w9 = (_Float16*)(buf1 + 9437184);
    _Float16* w9c2 = w9;
    _Float16* w9c3 = w9 + 73728;
    _Float16* w9c4 = w9 + 368640;
    _Float16* w9c5 = w9 + 958464;
    _Float16* w9c6 = w9 + 2138112;
    _Float16* w9c7 = w9 + 4497408;

    float* out0   = (float*)d_out;
    float* preds2 = (float*)d_out + (size_t)B * 10;

    hipMemsetAsync(small, 0, 512 * sizeof(float), stream);

    // ---- weight pre-transforms ----
    wsplit_kernel<<<(128 * 64   + 255) / 256, 256, 0, stream>>>(cw2, w9c2, 128 * 64);
    wsplit_kernel<<<(256 * 128  + 255) / 256, 256, 0, stream>>>(cw3, w9c3, 256 * 128);
    wsplit_kernel<<<(256 * 256  + 255) / 256, 256, 0, stream>>>(cw4, w9c4, 256 * 256);
    wsplit_kernel<<<(512 * 256  + 255) / 256, 256, 0, stream>>>(cw5, w9c5, 512 * 256);
    wsplit_kernel<<<(512 * 512  + 255) / 256, 256, 0, stream>>>(cw6, w9c6, 512 * 512);
    wsplit_kernel<<<(512 * 512  + 255) / 256, 256, 0, stream>>>(cw7, w9c7, 512 * 512);

    // ---- backbone ----
    conv3x3_kernel<3, 64, 64, 64, 1, false>
        <<<dim3(B * 4096 / 64, 1, 1), 256, 0, stream>>>(x, cw1, nullptr, buf0, B);
    bn_stats_kernel<64, 4096><<<dim3(64, 64), 256, 0, stream>>>(buf0, sums1, B);
    bn_finalize_kernel<64><<<1, 64, 0, stream>>>(sums1, bn1g, bn1b, ss1, B * 4096);
    maxpool_kernel<64, 64, 64, true>
        <<<(B * 64 * 32 * 32 + 255) / 256, 256, 0, stream>>>(buf0, ss1, buf1, B);

    // conv2: 64->128 @32x32
    conv_mfma_kernel<64, 128, 32, 32, 1, false>
        <<<dim3(B * 1024 / 128, 1, 1), 256, 0, stream>>>(buf1, w9c2, nullptr, buf0, B);
    bn_stats_kernel<128, 1024><<<dim3(128, 64), 256, 0, stream>>>(buf0, sums2, B);
    bn_finalize_kernel<128><<<2, 64, 0, stream>>>(sums2, bn2g, bn2b, ss2, B * 1024);
    maxpool_kernel<128, 32, 32, true>
        <<<(B * 128 * 16 * 16 + 255) / 256, 256, 0, stream>>>(buf0, ss2, buf1, B);

    // conv3: 128->256 @16x16 -> buf0[0..8.4M)
    conv_mfma_kernel<128, 256, 16, 16, 1, true>
        <<<dim3(B * 256 / 128, 2, 1), 256, 0, stream>>>(buf1, w9c3, cb3, buf0, B);
    // conv4: 256->256 @16x16 -> buf1[0..8.4M), pool -> buf0[0..2.1M)
    conv_mfma_kernel<256, 256, 16, 16, 1, true>
        <<<dim3(B * 256 / 128, 2, 1), 256, 0, stream>>>(buf0, w9c4, cb4, buf1, B);
    maxpool_kernel<256, 16, 16, false>
        <<<(B * 256 * 8 * 8 + 255) / 256, 256, 0, stream>>>(buf1, nullptr, buf0, B);

    // conv5: 256->512 @8x8, split-K=4 -> partials buf0+2.1M; sum -> buf1[0..4.2M)
    float* part5 = buf0 + 2097152;
    conv_mfma_kernel<256, 512, 8, 8, 4, false>
        <<<dim3(B * 64 / 128, 4, 4), 256, 0, stream>>>(buf0, w9c5, nullptr, part5, B);
    sum_bias_relu_kernel<512, 64, 4>
        <<<(B * 512 * 64 / 4 + 255) / 256, 256, 0, stream>>>(part5, cb5, buf1, B);

    // conv6: 512->512 @8x8, split-K=4 -> partials buf0[0..16.8M);
    // sum -> buf1+4.2M; pool -> buf1[0..1.05M)
    conv_mfma_kernel<512, 512, 8, 8, 4, false>
        <<<dim3(B * 64 / 128, 4, 4), 256, 0, stream>>>(buf1, w9c6, nullptr, buf0, B);
    sum_bias_relu_kernel<512, 64, 4>
        <<<(B * 512 * 64 / 4 + 255) / 256, 256, 0, stream>>>(buf0, cb6, buf1 + 4194304, B);
    maxpool_kernel<512, 8, 8, false>
        <<<(B * 512 * 4 * 4 + 255) / 256, 256, 0, stream>>>(buf1 + 4194304, nullptr, buf1, B);

    // conv7: 512->512 @4x4, split-K=8 -> partials buf0[0..8.4M)
    conv_mfma_kernel<512, 512, 4, 4, 8, false>
        <<<dim3(B * 16 / 128, 4, 8), 256, 0, stream>>>(buf1, w9c7, nullptr, buf0, B);

    // ---- colons ----
    hipMemsetAsync(Xb, 0, (size_t)16 * B * 592 * sizeof(float), stream);
    build_x_feats_kernel<8><<<(B * 512 + 255) / 256, 256, 0, stream>>>(buf0, cb7, Xb, B);

    // pass 1: pre = feats.W1[80:] + b1 (K=512); h = tanh(pre)
    colon_fc1_kernel<512, 80, 80, true, false>
        <<<dim3(10, B / 64, 16), 256, 0, stream>>>(Xb, W1, b1, preb, hb, B);
    colon_fc2_kernel<<<16, 128, 0, stream>>>(hb, W2, b2, preds1, B);

    // pass 2: h = tanh(neigh.W1[:80] + pre) (K=80)
    fill_neigh_kernel<<<(16 * B * 80 + 255) / 256, 256, 0, stream>>>(preds1, Xb, B);
    colon_fc1_kernel<80, 0, 0, false, true>
        <<<dim3(10, B / 64, 16), 256, 0, stream>>>(Xb, W1, b1, preb, hb, B);
    colon_fc2_kernel<<<16, 128, 0, stream>>>(hb, W2, b2, preds2, B);

    final_out_kernel<<<(B * 10 + 255) / 256, 256, 0, stream>>>(preds2, out0, B);
}

// Round 4
// 734.801 us; speedup vs baseline: 4.1418x; 1.3119x over previous
//
#include <hip/hip_runtime.h>
#include <math.h>

// ---------------------------------------------------------------------------
// Brain_49374944035335  R4: all activations f16 NHWC (K-dim contiguous ->
// vector staging), symmetric XOR-swizzled LDS tiles, conv1 on MFMA via
// compile-time im2col (K=27 pad 32). Convs: 128x128 tile, BK=32, f32 acc.
// ---------------------------------------------------------------------------

#define BN_EPS 1e-5f

typedef _Float16 f16x8 __attribute__((ext_vector_type(8)));
typedef _Float16 f16x4 __attribute__((ext_vector_type(4)));
typedef float    f32x4v __attribute__((ext_vector_type(4)));

constexpr int ilog2c(int x) { return x <= 1 ? 0 : 1 + ilog2c(x >> 1); }

// ---------------- weight pre-transform: OIHW fp32 -> [9][CO*CI] f16 --------
__global__ __launch_bounds__(256)
void wsplit_kernel(const float* __restrict__ w, _Float16* __restrict__ o, int COCI)
{
    const int t = blockIdx.x * 256 + threadIdx.x;
    if (t >= COCI) return;
#pragma unroll
    for (int ph = 0; ph < 9; ++ph)
        o[ph * COCI + t] = (_Float16)w[t * 9 + ph];
}

// conv1 weights: [64][3][3][3] fp32 -> [64][32] f16 (k = ci*9+ky*3+kx, pad)
__global__ void wsplit1_kernel(const float* __restrict__ w, _Float16* __restrict__ o)
{
    const int co = threadIdx.x;  // 64
#pragma unroll
    for (int k = 0; k < 32; ++k)
        o[co * 32 + k] = (k < 27) ? (_Float16)w[co * 27 + k] : (_Float16)0.f;
}

// ---------------- conv1: 3->64 @64x64, MFMA, one K-step (K=32) -------------
// in: NCHW fp32 [B][3][64][64]; out: NHWC f16 [B*4096][64]
__global__ __launch_bounds__(256)
void conv1_mfma_kernel(const float* __restrict__ in, const _Float16* __restrict__ w32,
                       _Float16* __restrict__ out, int B)
{
    __shared__ __align__(16) _Float16 As[64 * 32];
    __shared__ __align__(16) _Float16 Bs[128 * 32];

    const int tid  = threadIdx.x;
    const int pix0 = blockIdx.x * 128;
    const int bn   = tid & 127;
    const int bh   = tid >> 7;
    const int gp   = pix0 + bn;
    const int pb   = gp >> 12;
    const int sp   = gp & 4095;
    const int py   = sp >> 6;
    const int px   = sp & 63;
    const float* inb = in + (size_t)pb * 3 * 4096;

    // ---- stage B: 16 k-values, k = bh*16+u (compile-time per branch) ----
    _Float16 vals[16];
    if (bh == 0) {
#pragma unroll
        for (int u = 0; u < 16; ++u) {
            const int k = u;
            const int ci = k / 9, r = k - ci * 9, ky = r / 3, kx = r - ky * 3;
            const int iy = py + ky - 1, ix = px + kx - 1;
            float v = 0.f;
            if ((unsigned)iy < 64u && (unsigned)ix < 64u)
                v = inb[ci * 4096 + iy * 64 + ix];
            vals[u] = (_Float16)v;
        }
    } else {
#pragma unroll
        for (int u = 0; u < 16; ++u) {
            const int k = 16 + u;
            float v = 0.f;
            if (k < 27) {
                const int ci = k / 9, r = k - ci * 9, ky = r / 3, kx = r - ky * 3;
                const int iy = py + ky - 1, ix = px + kx - 1;
                if ((unsigned)iy < 64u && (unsigned)ix < 64u)
                    v = inb[ci * 4096 + iy * 64 + ix];
            }
            vals[u] = (_Float16)v;
        }
    }
    f16x8 b0, b1;
#pragma unroll
    for (int j = 0; j < 8; ++j) { b0[j] = vals[j]; b1[j] = vals[8 + j]; }
    *(f16x8*)&Bs[bn * 32 + (((2 * bh    ) ^ (bn & 3)) << 3)] = b0;
    *(f16x8*)&Bs[bn * 32 + (((2 * bh + 1) ^ (bn & 3)) << 3)] = b1;

    // ---- stage A (threads 0..127) ----
    if (tid < 128) {
        const int arow = tid >> 1, ah = tid & 1;
        const f16x8 a0 = *(const f16x8*)(w32 + arow * 32 + ah * 16);
        const f16x8 a1 = *(const f16x8*)(w32 + arow * 32 + ah * 16 + 8);
        *(f16x8*)&As[arow * 32 + (((2 * ah    ) ^ (arow & 3)) << 3)] = a0;
        *(f16x8*)&As[arow * 32 + (((2 * ah + 1) ^ (arow & 3)) << 3)] = a1;
    }
    __syncthreads();

    const int lane = tid & 63, wv = tid >> 6;
    const int q = lane >> 4, lm = lane & 15;
    const int swz = (q ^ (lm & 3)) << 3;

    f16x8 af[4], bf[2];
#pragma unroll
    for (int ti = 0; ti < 4; ++ti)
        af[ti] = *(const f16x8*)&As[(ti * 16 + lm) * 32 + swz];
#pragma unroll
    for (int tj = 0; tj < 2; ++tj)
        bf[tj] = *(const f16x8*)&Bs[(wv * 32 + tj * 16 + lm) * 32 + swz];

    f32x4v acc[4][2];
#pragma unroll
    for (int ti = 0; ti < 4; ++ti)
#pragma unroll
        for (int tj = 0; tj < 2; ++tj)
            acc[ti][tj] = __builtin_amdgcn_mfma_f32_16x16x32_f16(
                af[ti], bf[tj], (f32x4v)0.f, 0, 0, 0);

#pragma unroll
    for (int tj = 0; tj < 2; ++tj) {
        const int gpix = pix0 + wv * 32 + tj * 16 + lm;
#pragma unroll
        for (int ti = 0; ti < 4; ++ti) {
            const int cob = ti * 16 + q * 4;
            f16x4 h4;
#pragma unroll
            for (int r = 0; r < 4; ++r) h4[r] = (_Float16)acc[ti][tj][r];
            *(f16x4*)&out[(size_t)gpix * 64 + cob] = h4;
        }
    }
}

// ---------------- main NHWC MFMA conv: 3x3 SAME as 9 shifted GEMMs ---------
// in/out NHWC f16; w9 [ph][CO][CI] f16. EPI: 0=f16 plain, 1=bias+relu f16,
// 2=fp32 split-K partial.
template <int CI, int CO, int H, int W, int KSPLIT, int EPI>
__global__ __launch_bounds__(256)
void conv_nhwc_kernel(const _Float16* __restrict__ in, const _Float16* __restrict__ w9,
                      const float* __restrict__ bias, _Float16* __restrict__ out,
                      float* __restrict__ part, int B)
{
    constexpr int HW   = H * W;
    constexpr int lgHW = ilog2c(HW);
    constexpr int lgW  = ilog2c(W);

    __shared__ __align__(16) _Float16 As[128 * 32];
    __shared__ __align__(16) _Float16 Bs[128 * 32];

    const int tid  = threadIdx.x;
    const int pix0 = blockIdx.x * 128;
    const int co0  = blockIdx.y * 128;

    const int bn = tid & 127;
    const int bh = tid >> 7;
    const int gp = pix0 + bn;
    const int pb = gp >> lgHW;
    const int sp = gp & (HW - 1);
    const int py = sp >> lgW;
    const int px = sp & (W - 1);

    const int arow = tid >> 1;
    const int ah   = tid & 1;

    const int lane = tid & 63, wv = tid >> 6;
    const int wm = (wv & 1) * 64;
    const int wn = (wv >> 1) * 64;
    const int q = lane >> 4, lm = lane & 15;
    const int swz = (q ^ (lm & 3)) << 3;

    const int bw0 = ((2 * bh    ) ^ (bn & 3)) << 3;
    const int bw1 = ((2 * bh + 1) ^ (bn & 3)) << 3;
    const int aw0 = ((2 * ah    ) ^ (arow & 3)) << 3;
    const int aw1 = ((2 * ah + 1) ^ (arow & 3)) << 3;

    f32x4v acc[4][4];
#pragma unroll
    for (int i = 0; i < 4; ++i)
#pragma unroll
        for (int j = 0; j < 4; ++j) acc[i][j] = (f32x4v)0.f;

    constexpr int CS_TOT = CI / 32;
    constexpr int CS_PER = CS_TOT / KSPLIT;
    const int cs0 = (KSPLIT > 1) ? blockIdx.z * CS_PER : 0;

    for (int ph = 0; ph < 9; ++ph) {
        const int dy = ph / 3 - 1;
        const int dx = ph - (ph / 3) * 3 - 1;
        const int y2 = py + dy;
        const int x2 = px + dx;
        const bool valid = ((unsigned)y2 < (unsigned)H) && ((unsigned)x2 < (unsigned)W);
        const _Float16 msk = valid ? (_Float16)1.f : (_Float16)0.f;
        const int sp2 = valid ? ((y2 << lgW) | x2) : 0;
        const _Float16* bsrc = in + ((size_t)((pb << lgHW) | sp2)) * CI + bh * 16;
        const _Float16* asrc = w9 + ((size_t)(ph * CO) + co0 + arow) * CI + ah * 16;

        for (int cs = cs0; cs < cs0 + CS_PER; ++cs) {
            f16x8 bv0 = *(const f16x8*)(bsrc + cs * 32);
            f16x8 bv1 = *(const f16x8*)(bsrc + cs * 32 + 8);
            const f16x8 av0 = *(const f16x8*)(asrc + cs * 32);
            const f16x8 av1 = *(const f16x8*)(asrc + cs * 32 + 8);

            __syncthreads();   // previous tile's frag reads done
            bv0 *= msk;
            bv1 *= msk;
            *(f16x8*)&Bs[bn * 32 + bw0]   = bv0;
            *(f16x8*)&Bs[bn * 32 + bw1]   = bv1;
            *(f16x8*)&As[arow * 32 + aw0] = av0;
            *(f16x8*)&As[arow * 32 + aw1] = av1;
            __syncthreads();

            f16x8 af[4], bf[4];
#pragma unroll
            for (int ti = 0; ti < 4; ++ti)
                af[ti] = *(const f16x8*)&As[(wm + ti * 16 + lm) * 32 + swz];
#pragma unroll
            for (int tj = 0; tj < 4; ++tj)
                bf[tj] = *(const f16x8*)&Bs[(wn + tj * 16 + lm) * 32 + swz];
#pragma unroll
            for (int ti = 0; ti < 4; ++ti)
#pragma unroll
                for (int tj = 0; tj < 4; ++tj)
                    acc[ti][tj] = __builtin_amdgcn_mfma_f32_16x16x32_f16(
                        af[ti], bf[tj], acc[ti][tj], 0, 0, 0);
        }
    }

    // epilogue: C[m=cout][n=pixel]; col=lane&15, row=quad*4+reg
    if (EPI == 2) {
        float* pout = part + (size_t)blockIdx.z * ((size_t)B * HW * CO);
#pragma unroll
        for (int tj = 0; tj < 4; ++tj) {
            const int gpix = pix0 + wn + tj * 16 + lm;
#pragma unroll
            for (int ti = 0; ti < 4; ++ti) {
                const int cob = co0 + wm + ti * 16 + q * 4;
                *(float4*)&pout[(size_t)gpix * CO + cob] =
                    make_float4(acc[ti][tj][0], acc[ti][tj][1],
                                acc[ti][tj][2], acc[ti][tj][3]);
            }
        }
    } else {
#pragma unroll
        for (int tj = 0; tj < 4; ++tj) {
            const int gpix = pix0 + wn + tj * 16 + lm;
#pragma unroll
            for (int ti = 0; ti < 4; ++ti) {
                const int cob = co0 + wm + ti * 16 + q * 4;
                f16x4 h4;
                if (EPI == 1) {
                    const float4 bb = *(const float4*)&bias[cob];
                    h4[0] = (_Float16)fmaxf(acc[ti][tj][0] + bb.x, 0.f);
                    h4[1] = (_Float16)fmaxf(acc[ti][tj][1] + bb.y, 0.f);
                    h4[2] = (_Float16)fmaxf(acc[ti][tj][2] + bb.z, 0.f);
                    h4[3] = (_Float16)fmaxf(acc[ti][tj][3] + bb.w, 0.f);
                } else {
#pragma unroll
                    for (int r = 0; r < 4; ++r) h4[r] = (_Float16)acc[ti][tj][r];
                }
                *(f16x4*)&out[(size_t)gpix * CO + cob] = h4;
            }
        }
    }
}

// ---------------- BN stats over NHWC f16 -----------------------------------
template <int C>
__global__ __launch_bounds__(256)
void bn_stats_nhwc_kernel(const _Float16* __restrict__ in, float* __restrict__ sums,
                          int Ptot)
{
    constexpr int C8 = C / 8;
    constexpr int PS = 256 / C8;
    const int chunk = Ptot / gridDim.x;
    const int c8   = threadIdx.x & (C8 - 1);
    const int poff = threadIdx.x >> ilog2c(C8);
    float s[8], s2[8];
#pragma unroll
    for (int j = 0; j < 8; ++j) { s[j] = 0.f; s2[j] = 0.f; }
    const int p0 = blockIdx.x * chunk;
    for (int p = p0 + poff; p < p0 + chunk; p += PS) {
        const f16x8 v = *(const f16x8*)(in + (size_t)p * C + c8 * 8);
#pragma unroll
        for (int j = 0; j < 8; ++j) {
            const float f = (float)v[j];
            s[j] += f; s2[j] += f * f;
        }
    }
    __shared__ float ls[2 * C];
    for (int i = threadIdx.x; i < 2 * C; i += 256) ls[i] = 0.f;
    __syncthreads();
#pragma unroll
    for (int j = 0; j < 8; ++j) {
        atomicAdd(&ls[c8 * 8 + j], s[j]);
        atomicAdd(&ls[C + c8 * 8 + j], s2[j]);
    }
    __syncthreads();
    for (int i = threadIdx.x; i < 2 * C; i += 256) atomicAdd(&sums[i], ls[i]);
}

template <int C>
__global__ void bn_finalize_kernel(const float* __restrict__ sums,
                                   const float* __restrict__ g,
                                   const float* __restrict__ beta,
                                   float* __restrict__ ss, int Ntot)
{
    const int c = blockIdx.x * 64 + threadIdx.x;
    if (c >= C) return;
    const float inv   = 1.f / (float)Ntot;
    const float mean  = sums[c] * inv;
    const float var   = sums[C + c] * inv - mean * mean;
    const float scale = g[c] * rsqrtf(var + BN_EPS);
    ss[c]     = scale;
    ss[C + c] = beta[c] - mean * scale;
}

// ---------------- maxpool k3 s2 p1, NHWC f16 (opt fused BN+ReLU) -----------
template <int C, int Hin, int Win, bool DO_BN>
__global__ __launch_bounds__(256)
void pool_nhwc_kernel(const _Float16* __restrict__ in, const float* __restrict__ ss,
                      _Float16* __restrict__ out, int B)
{
    constexpr int Ho = Hin / 2, Wo = Win / 2, C8 = C / 8;
    constexpr int lgC8 = ilog2c(C8), lgWo = ilog2c(Wo), lgHo = ilog2c(Ho);
    const int t = blockIdx.x * 256 + threadIdx.x;
    const int total = B * Ho * Wo * C8;
    if (t >= total) return;
    const int c8 = t & (C8 - 1);
    const int r1 = t >> lgC8;
    const int ox = r1 & (Wo - 1);
    const int r2 = r1 >> lgWo;
    const int oy = r2 & (Ho - 1);
    const int b  = r2 >> lgHo;

    float sc[8], sh[8];
    if (DO_BN) {
#pragma unroll
        for (int j = 0; j < 8; ++j) {
            sc[j] = ss[c8 * 8 + j];
            sh[j] = ss[C + c8 * 8 + j];
        }
    }
    float m[8];
#pragma unroll
    for (int j = 0; j < 8; ++j) m[j] = -1e30f;

    const int y0 = max(0, 2 * oy - 1), y1 = min(Hin - 1, 2 * oy + 1);
    const int x0 = max(0, 2 * ox - 1), x1 = min(Win - 1, 2 * ox + 1);
    const _Float16* ib = in + ((size_t)b * Hin * Win) * C + c8 * 8;
    for (int iy = y0; iy <= y1; ++iy)
        for (int ix = x0; ix <= x1; ++ix) {
            const f16x8 v = *(const f16x8*)(ib + (size_t)(iy * Win + ix) * C);
#pragma unroll
            for (int j = 0; j < 8; ++j) {
                float f = (float)v[j];
                if (DO_BN) f = f * sc[j] + sh[j];
                m[j] = fmaxf(m[j], f);
            }
        }
    f16x8 o;
#pragma unroll
    for (int j = 0; j < 8; ++j) {
        float f = m[j];
        if (DO_BN) f = fmaxf(f, 0.f);
        o[j] = (_Float16)f;
    }
    *(f16x8*)&out[((size_t)((b << (lgHo + lgWo)) | (oy << lgWo) | ox)) * C + c8 * 8] = o;
}

// ---------------- split-K partial reduce -> f16 NHWC -----------------------
template <int CO, int Z>
__global__ __launch_bounds__(256)
void sum_bias_relu_nhwc_kernel(const float* __restrict__ part, const float* __restrict__ bias,
                               _Float16* __restrict__ out, int Npix)
{
    const int t = blockIdx.x * 256 + threadIdx.x;
    const int N8 = Npix * CO / 8;
    if (t >= N8) return;
    const size_t i8 = (size_t)t * 8;
    const int c = (int)(i8 & (CO - 1));
    const size_t S = (size_t)Npix * CO;
    float4 x0 = *(const float4*)(part + i8);
    float4 x1 = *(const float4*)(part + i8 + 4);
#pragma unroll
    for (int z = 1; z < Z; ++z) {
        const float4 p0 = *(const float4*)(part + z * S + i8);
        const float4 p1 = *(const float4*)(part + z * S + i8 + 4);
        x0.x += p0.x; x0.y += p0.y; x0.z += p0.z; x0.w += p0.w;
        x1.x += p1.x; x1.y += p1.y; x1.z += p1.z; x1.w += p1.w;
    }
    const float4 b0 = *(const float4*)(bias + c);
    const float4 b1 = *(const float4*)(bias + c + 4);
    f16x8 o;
    o[0] = (_Float16)fmaxf(x0.x + b0.x, 0.f);
    o[1] = (_Float16)fmaxf(x0.y + b0.y, 0.f);
    o[2] = (_Float16)fmaxf(x0.z + b0.z, 0.f);
    o[3] = (_Float16)fmaxf(x0.w + b0.w, 0.f);
    o[4] = (_Float16)fmaxf(x1.x + b1.x, 0.f);
    o[5] = (_Float16)fmaxf(x1.y + b1.y, 0.f);
    o[6] = (_Float16)fmaxf(x1.z + b1.z, 0.f);
    o[7] = (_Float16)fmaxf(x1.w + b1.w, 0.f);
    *(f16x8*)&out[i8] = o;
}

// ---------------- conv7 partials -> X feats (fp32) -------------------------
// part [Z][B*16][512] f32 NHWC; X[sp][b][80+c] = relu(sum + bias)
template <int Z>
__global__ __launch_bounds__(256)
void build_x_kernel(const float* __restrict__ part, const float* __restrict__ bias,
                    float* __restrict__ X, int B)
{
    const int t = blockIdx.x * 256 + threadIdx.x;
    if (t >= B * 16 * 128) return;
    const int pix = t >> 7;
    const int c   = (t & 127) * 4;
    const size_t S = (size_t)B * 16 * 512;
    float4 a = *(const float4*)(part + (size_t)pix * 512 + c);
#pragma unroll
    for (int z = 1; z < Z; ++z) {
        const float4 p = *(const float4*)(part + z * S + (size_t)pix * 512 + c);
        a.x += p.x; a.y += p.y; a.z += p.z; a.w += p.w;
    }
    const float4 bb = *(const float4*)(bias + c);
    a.x = fmaxf(a.x + bb.x, 0.f);
    a.y = fmaxf(a.y + bb.y, 0.f);
    a.z = fmaxf(a.z + bb.z, 0.f);
    a.w = fmaxf(a.w + bb.w, 0.f);
    const int b_ = pix >> 4, sp = pix & 15;
    *(float4*)&X[((size_t)(sp * B + b_)) * 592 + 80 + c] = a;
}

// ---------------- colons fc1 (fp32, generic K / pre handling) --------------
template <int K, int XOFF, int WOFF, bool WRITE_PRE, bool ADD_PRE>
__global__ __launch_bounds__(256)
void colon_fc1_kernel(const float* __restrict__ X, const float* __restrict__ W1,
                      const float* __restrict__ b1, float* __restrict__ pre,
                      float* __restrict__ h, int B)
{
    constexpr int N = 600, BK = 16;
    const int n  = blockIdx.z;
    const int m0 = blockIdx.y * 64;
    const int o0 = blockIdx.x * 64;

    __shared__ __align__(16) float As[BK][68];
    __shared__ __align__(16) float Bs[BK][68];

    const int tid = threadIdx.x;
    const int tx = tid & 15, ty = tid >> 4;
    const int a_m = tid >> 2, a_k4 = (tid & 3) * 4;
    const int b_o = tid & 63, b_kr = tid >> 6;

    const float* Xn  = X  + (size_t)n * B * 592;
    const float* W1n = W1 + (size_t)n * 592 * N;

    float acc[4][4];
#pragma unroll
    for (int i = 0; i < 4; ++i)
#pragma unroll
        for (int j = 0; j < 4; ++j) acc[i][j] = 0.f;

    for (int kb = 0; kb < K; kb += BK) {
        const float4 av = *reinterpret_cast<const float4*>(
            &Xn[(size_t)(m0 + a_m) * 592 + XOFF + kb + a_k4]);
        As[a_k4 + 0][a_m] = av.x;
        As[a_k4 + 1][a_m] = av.y;
        As[a_k4 + 2][a_m] = av.z;
        As[a_k4 + 3][a_m] = av.w;
#pragma unroll
        for (int i = 0; i < 4; ++i) {
            const int kl = b_kr + i * 4;
            const int o  = o0 + b_o;
            Bs[kl][b_o] = (o < N) ? W1n[(size_t)(WOFF + kb + kl) * N + o] : 0.f;
        }
        __syncthreads();
#pragma unroll
        for (int kk = 0; kk < BK; ++kk) {
            const float4 a4 = *reinterpret_cast<const float4*>(&As[kk][ty * 4]);
            const float4 b4 = *reinterpret_cast<const float4*>(&Bs[kk][tx * 4]);
            const float a0[4] = {a4.x, a4.y, a4.z, a4.w};
            const float b0[4] = {b4.x, b4.y, b4.z, b4.w};
#pragma unroll
            for (int i = 0; i < 4; ++i)
#pragma unroll
                for (int j = 0; j < 4; ++j)
                    acc[i][j] += a0[i] * b0[j];
        }
        __syncthreads();
    }

#pragma unroll
    for (int i = 0; i < 4; ++i) {
        const int m = m0 + ty * 4 + i;
#pragma unroll
        for (int j = 0; j < 4; ++j) {
            const int o = o0 + tx * 4 + j;
            if (o < N) {
                const size_t oi = ((size_t)(n * B + m)) * N + o;
                float v = acc[i][j] + (ADD_PRE ? pre[oi] : b1[n * N + o]);
                if (WRITE_PRE) pre[oi] = v;
                h[oi] = tanhf(v);
            }
        }
    }
}

// ---------------- colons fc2 + softmax -------------------------------------
__global__ __launch_bounds__(128)
void colon_fc2_kernel(const float* __restrict__ h, const float* __restrict__ W2,
                      const float* __restrict__ b2, float* __restrict__ preds, int B)
{
    const int n = blockIdx.x;
    __shared__ float W2s[6000];
    __shared__ float b2s[10];
    for (int i = threadIdx.x; i < 6000; i += 128) W2s[i] = W2[n * 6000 + i];
    if (threadIdx.x < 10) b2s[threadIdx.x] = b2[n * 10 + threadIdx.x];
    __syncthreads();

    for (int b = threadIdx.x; b < B; b += 128) {
        float l[10];
#pragma unroll
        for (int c = 0; c < 10; ++c) l[c] = b2s[c];
        const float* hp = h + ((size_t)(n * B + b)) * 600;
        for (int k = 0; k < 600; k += 4) {
            const float4 hv = *reinterpret_cast<const float4*>(&hp[k]);
            const float hh[4] = {hv.x, hv.y, hv.z, hv.w};
#pragma unroll
            for (int u = 0; u < 4; ++u)
#pragma unroll
                for (int c = 0; c < 10; ++c)
                    l[c] += hh[u] * W2s[(k + u) * 10 + c];
        }
        float mx = l[0];
#pragma unroll
        for (int c = 1; c < 10; ++c) mx = fmaxf(mx, l[c]);
        float s = 0.f;
#pragma unroll
        for (int c = 0; c < 10; ++c) { l[c] = expf(l[c] - mx); s += l[c]; }
        const float inv = 1.f / s;
        float* pp = preds + ((size_t)(n * B + b)) * 10;
#pragma unroll
        for (int c = 0; c < 10; ++c) pp[c] = l[c] * inv;
    }
}

// ---------------- neighbor gather ------------------------------------------
__global__ __launch_bounds__(256)
void fill_neigh_kernel(const float* __restrict__ preds1, float* __restrict__ X, int B)
{
    const int t = blockIdx.x * 256 + threadIdx.x;
    if (t >= 16 * B * 80) return;
    const int c = t % 10;
    const int j = (t / 10) & 7;
    const int b = (t / 80) % B;
    const int n = t / (80 * B);

    int lst[8];
    int cnt = 0;
    const int w = 4, sz = 16, i = n;
    if (i - w >= 0)                                lst[cnt++] = i - w;
    if (i % w != 0)                                lst[cnt++] = i - 1;
    if ((i + 1) % w != 0)                          lst[cnt++] = i + 1;
    if (i + w < sz)                                lst[cnt++] = i + w;
    if (i - w - 1 >= 0 && i % w != 0)              lst[cnt++] = i - w - 1;
    if (i - w + 1 >= 0 && (i + 1) % w != 0)        lst[cnt++] = i - w + 1;
    if (i + w - 1 < sz && i % w != 0)              lst[cnt++] = i + w - 1;
    if (i + w + 1 < sz && (i + 1) % w != 0)        lst[cnt++] = i + w + 1;

    float v = 0.f;
    if (j < cnt) v = preds1[((size_t)(lst[j] * B + b)) * 10 + c];
    X[((size_t)(n * B + b)) * 592 + j * 10 + c] = v;
}

// ---------------- final ----------------------------------------------------
__global__ __launch_bounds__(256)
void final_out_kernel(const float* __restrict__ preds2, float* __restrict__ out0, int B)
{
    const int t = blockIdx.x * 256 + threadIdx.x;
    if (t >= B * 10) return;
    const int b = t / 10, c = t % 10;
    float s = 0.f;
#pragma unroll
    for (int n = 0; n < 16; ++n)
        s += preds2[((size_t)(n * B + b)) * 10 + c];
    const float m = s * (1.f / 16.f);
    out0[t] = m * m;
}

// ---------------------------------------------------------------------------
extern "C" void kernel_launch(void* const* d_in, const int* in_sizes, int n_in,
                              void* d_out, int out_size, void* d_ws, size_t ws_size,
                              hipStream_t stream)
{
    const float* x    = (const float*)d_in[0];
    const float* cw1  = (const float*)d_in[1];
    const float* bn1g = (const float*)d_in[3];
    const float* bn1b = (const float*)d_in[4];
    const float* cw2  = (const float*)d_in[5];
    const float* bn2g = (const float*)d_in[7];
    const float* bn2b = (const float*)d_in[8];
    const float* cw3  = (const float*)d_in[9];
    const float* cb3  = (const float*)d_in[10];
    const float* cw4  = (const float*)d_in[11];
    const float* cb4  = (const float*)d_in[12];
    const float* cw5  = (const float*)d_in[13];
    const float* cb5  = (const float*)d_in[14];
    const float* cw6  = (const float*)d_in[15];
    const float* cb6  = (const float*)d_in[16];
    const float* cw7  = (const float*)d_in[17];
    const float* cb7  = (const float*)d_in[18];
    const float* W1   = (const float*)d_in[19];
    const float* b1   = (const float*)d_in[20];
    const float* W2   = (const float*)d_in[21];
    const float* b2   = (const float*)d_in[22];

    const int B = in_sizes[0] / (3 * 64 * 64);   // 128

    // ---- workspace layout (f32 units from base) ----
    float* ws = (float*)d_ws;
    float*     P    = ws;                                   // fp32 partials, 16.8M f32
    _Float16*  A    = (_Float16*)(ws + 16777216);           // f16 act, 33.6M f16
    _Float16*  Bb   = (_Float16*)(ws + 33554432);           // f16 act, 16.8M f16
    _Float16*  wreg = (_Float16*)(ws + 41943040);           // f16 weights
    float*     Xb   = ws + 45371392;                        // [16][B][592]
    float*     hb   = ws + 46583808;                        // [16][B][600]
    float*     preb = ws + 47812608;                        // [16][B][600]
    float*     small= ws + 49041408;
    float* sums1  = small;          // 128
    float* sums2  = small + 256;    // 256
    float* ss1    = small + 1024;   // 128
    float* ss2    = small + 1536;   // 256
    float* preds1 = small + 2048;   // 16*B*10

    _Float16* w1f  = wreg;                  // 2048
    _Float16* w9c2 = wreg + 2048;           // 73728
    _Float16* w9c3 = w9c2 + 73728;          // 294912
    _Float16* w9c4 = w9c3 + 294912;         // 589824
    _Float16* w9c5 = w9c4 + 589824;         // 1179648
    _Float16* w9c6 = w9c5 + 1179648;        // 2359296
    _Float16* w9c7 = w9c6 + 2359296;        // 2359296

    float* out0   = (float*)d_out;
    float* preds2 = (float*)d_out + (size_t)B * 10;

    hipMemsetAsync(small, 0, 512 * sizeof(float), stream);

    // ---- weight pre-transforms ----
    wsplit1_kernel<<<1, 64, 0, stream>>>(cw1, w1f);
    wsplit_kernel<<<(128 * 64  + 255) / 256, 256, 0, stream>>>(cw2, w9c2, 128 * 64);
    wsplit_kernel<<<(256 * 128 + 255) / 256, 256, 0, stream>>>(cw3, w9c3, 256 * 128);
    wsplit_kernel<<<(256 * 256 + 255) / 256, 256, 0, stream>>>(cw4, w9c4, 256 * 256);
    wsplit_kernel<<<(512 * 256 + 255) / 256, 256, 0, stream>>>(cw5, w9c5, 512 * 256);
    wsplit_kernel<<<(512 * 512 + 255) / 256, 256, 0, stream>>>(cw6, w9c6, 512 * 512);
    wsplit_kernel<<<(512 * 512 + 255) / 256, 256, 0, stream>>>(cw7, w9c7, 512 * 512);

    // ---- backbone (all acts f16 NHWC) ----
    // conv1: 3->64 @64x64 -> A [524288][64]
    conv1_mfma_kernel<<<B * 4096 / 128, 256, 0, stream>>>(x, w1f, A, B);
    bn_stats_nhwc_kernel<64><<<512, 256, 0, stream>>>(A, sums1, B * 4096);
    bn_finalize_kernel<64><<<1, 64, 0, stream>>>(sums1, bn1g, bn1b, ss1, B * 4096);
    pool_nhwc_kernel<64, 64, 64, true>
        <<<(B * 1024 * 8 + 255) / 256, 256, 0, stream>>>(A, ss1, Bb, B);

    // conv2: 64->128 @32x32 -> A [131072][128]
    conv_nhwc_kernel<64, 128, 32, 32, 1, 0>
        <<<dim3(B * 1024 / 128, 1), 256, 0, stream>>>(Bb, w9c2, nullptr, A, nullptr, B);
    bn_stats_nhwc_kernel<128><<<256, 256, 0, stream>>>(A, sums2, B * 1024);
    bn_finalize_kernel<128><<<2, 64, 0, stream>>>(sums2, bn2g, bn2b, ss2, B * 1024);
    pool_nhwc_kernel<128, 32, 32, true>
        <<<(B * 256 * 16 + 255) / 256, 256, 0, stream>>>(A, ss2, Bb, B);

    // conv3: 128->256 @16x16 -> A; conv4: 256->256 -> Bb; pool3 -> A
    conv_nhwc_kernel<128, 256, 16, 16, 1, 1>
        <<<dim3(B * 256 / 128, 2), 256, 0, stream>>>(Bb, w9c3, cb3, A, nullptr, B);
    conv_nhwc_kernel<256, 256, 16, 16, 1, 1>
        <<<dim3(B * 256 / 128, 2), 256, 0, stream>>>(A, w9c4, cb4, Bb, nullptr, B);
    pool_nhwc_kernel<256, 16, 16, false>
        <<<(B * 64 * 32 + 255) / 256, 256, 0, stream>>>(Bb, nullptr, A, B);

    // conv5: 256->512 @8x8, split-K=2 -> P; sum -> Bb
    conv_nhwc_kernel<256, 512, 8, 8, 2, 2>
        <<<dim3(B * 64 / 128, 4, 2), 256, 0, stream>>>(A, w9c5, nullptr, nullptr, P, B);
    sum_bias_relu_nhwc_kernel<512, 2>
        <<<(B * 64 * 512 / 8 + 255) / 256, 256, 0, stream>>>(P, cb5, Bb, B * 64);

    // conv6: 512->512 @8x8, split-K=2 -> P; sum -> A; pool4 -> Bb
    conv_nhwc_kernel<512, 512, 8, 8, 2, 2>
        <<<dim3(B * 64 / 128, 4, 2), 256, 0, stream>>>(Bb, w9c6, nullptr, nullptr, P, B);
    sum_bias_relu_nhwc_kernel<512, 2>
        <<<(B * 64 * 512 / 8 + 255) / 256, 256, 0, stream>>>(P, cb6, A, B * 64);
    pool_nhwc_kernel<512, 8, 8, false>
        <<<(B * 16 * 64 + 255) / 256, 256, 0, stream>>>(A, nullptr, Bb, B);

    // conv7: 512->512 @4x4, split-K=8 -> P
    conv_nhwc_kernel<512, 512, 4, 4, 8, 2>
        <<<dim3(B * 16 / 128, 4, 8), 256, 0, stream>>>(Bb, w9c7, nullptr, nullptr, P, B);

    // ---- colons ----
    build_x_kernel<8><<<(B * 16 * 128 + 255) / 256, 256, 0, stream>>>(P, cb7, Xb, B);

    // pass 1: pre = feats.W1[80:] + b1 (K=512); h = tanh(pre)
    colon_fc1_kernel<512, 80, 80, true, false>
        <<<dim3(10, B / 64, 16), 256, 0, stream>>>(Xb, W1, b1, preb, hb, B);
    colon_fc2_kernel<<<16, 128, 0, stream>>>(hb, W2, b2, preds1, B);

    // pass 2: h = tanh(neigh.W1[:80] + pre) (K=80)
    fill_neigh_kernel<<<(16 * B * 80 + 255) / 256, 256, 0, stream>>>(preds1, Xb, B);
    colon_fc1_kernel<80, 0, 0, false, true>
        <<<dim3(10, B / 64, 16), 256, 0, stream>>>(Xb, W1, b1, preb, hb, B);
    colon_fc2_kernel<<<16, 128, 0, stream>>>(hb, W2, b2, preds2, B);

    final_out_kernel<<<(B * 10 + 255) / 256, 256, 0, stream>>>(preds2, out0, B);
}